// Round 1
// baseline (512.944 us; speedup 1.0000x reference)
//
#include <hip/hip_runtime.h>
#include <hip/hip_bf16.h>
#include <stdint.h>
#include <stddef.h>

// ---------------------------------------------------------------------------
// MultiHeadAttention: q/k/v = X @ W.T + b ; flash-attn per head ; out @ Wo.T+bo
// FP32 in/out buffers; bf16 MFMA internally.
// B=4 S=2048 D=1024 H=16 Dh=64 -> M = B*S = 8192
// Round 6: swapped-operand QK^T (S^T = mfma(K,Q)) + key-permuted V^T so the
// exp'd scores ARE the PV A-fragment in-register: no P LDS round-trip at all
// (sP buffer deleted, LDS 50->32 KB). log2e folded into the K projection
// epilogue (softmax = bare exp2). XCD swizzle: each XCD owns 8 whole heads
// (K+V = 4 MB = one XCD L2).
// ---------------------------------------------------------------------------

typedef __bf16 bf16_t;
typedef __bf16 bf16x4 __attribute__((ext_vector_type(4)));
typedef __bf16 bf16x8 __attribute__((ext_vector_type(8)));
typedef float f32x4 __attribute__((ext_vector_type(4)));

#define D_MODEL 1024
#define M_ROWS  8192
#define S_LEN   2048
#define N_HEADS 16
#define HEAD_DIM 64
#define GBK 32

__device__ __forceinline__ void async_copy16(void* lds, const void* g) {
    __builtin_amdgcn_global_load_lds(
        (const __attribute__((address_space(1))) void*)g,
        (__attribute__((address_space(3))) void*)lds, 16, 0, 0);
}

// ---------------------------------------------------------------------------
// Projection GEMM: C[m,n] = sum_k A[m,k]*W[n,k] + bias[n]
// A,W,bias fp32; C bf16. 128x128 tile, BK=32, 256 thr (4 waves, 2x2 of 64x64).
// z==1 (K proj): output pre-scaled by log2e (softmax then needs bare exp2).
// z==2 (V proj): output transposed per head [b][dh][s], with keys PERMUTED
// within each 32-key chunk: pos = c*32 + p*8 + g*4 + e  <-  key = c*32 + g*16
// + p*4 + e. This makes the PV B-fragment of attn read the same k-ordering
// the swapped-QK^T scores naturally sit in (dot product is k-order-invariant).
// ---------------------------------------------------------------------------
__global__ __launch_bounds__(256, 3) void gemm_proj(
    const float* __restrict__ A0, const float* __restrict__ W0, const float* __restrict__ b0,
    const float* __restrict__ A1, const float* __restrict__ W1, const float* __restrict__ b1,
    const float* __restrict__ A2, const float* __restrict__ W2, const float* __restrict__ b2,
    bf16_t* C0, bf16_t* C1, bf16_t* C2)
{
    const float* A; const float* W; const float* bias; bf16_t* C;
    const int z = blockIdx.z;
    if (z == 0)      { A = A0; W = W0; bias = b0; C = C0; }
    else if (z == 1) { A = A1; W = W1; bias = b1; C = C1; }
    else             { A = A2; W = W2; bias = b2; C = C2; }
    const float cs = (z == 1) ? 1.4426950408889634f : 1.0f;  // log2e into kb

    __align__(16) __shared__ bf16_t sA[2][128 * GBK];   // 8 KB per buf
    __align__(16) __shared__ bf16_t sB[2][128 * GBK];

    const int t    = threadIdx.x;
    const int lane = t & 63;
    const int w    = t >> 6;
    const int wm   = (w & 1) * 64;
    const int wn   = (w >> 1) * 64;
    const int bm0  = blockIdx.y * 128;
    const int bn0  = blockIdx.x * 128;
    const int q4   = lane >> 4;
    const int l16  = lane & 15;

    // staging role: row = t>>1, 16-elem k-half = (t&1)*16 (2 16B chunks)
    const int srow  = t >> 1;
    const int cbase = (t & 1) * 2;
    const float* aptr = &A[(size_t)(bm0 + srow) * D_MODEL + cbase * 8];
    const float* wptr = &W[(size_t)(bn0 + srow) * D_MODEL + cbase * 8];

    f32x4 ar[4], wr[4];
#pragma unroll
    for (int c = 0; c < 4; c++) {
        ar[c] = *(const f32x4*)(aptr + c * 4);
        wr[c] = *(const f32x4*)(wptr + c * 4);
    }

    f32x4 acc[4][4];
    const f32x4 zero4 = {0.f, 0.f, 0.f, 0.f};
#pragma unroll
    for (int i = 0; i < 4; i++)
#pragma unroll
        for (int j = 0; j < 4; j++) acc[i][j] = zero4;

    for (int kt = 0; kt < D_MODEL / GBK; ++kt) {
        bf16_t* cA = sA[kt & 1];
        bf16_t* cB = sB[kt & 1];
        // cvt regs (tile kt) -> swizzled bf16 LDS. chunk c stored at c^(row&3).
        bf16x8 abf[2], wbf[2];
#pragma unroll
        for (int c = 0; c < 4; c++)
#pragma unroll
            for (int j = 0; j < 4; j++) {
                abf[c >> 1][(c & 1) * 4 + j] = (bf16_t)ar[c][j];
                wbf[c >> 1][(c & 1) * 4 + j] = (bf16_t)wr[c][j];
            }
#pragma unroll
        for (int hb = 0; hb < 2; hb++) {
            const int slot = (cbase + hb) ^ (srow & 3);
            *(bf16x8*)&cA[srow * GBK + slot * 8] = abf[hb];
            *(bf16x8*)&cB[srow * GBK + slot * 8] = wbf[hb];
        }
        __syncthreads();   // write(kt) visible; prior-buf reads already done
        if (kt < D_MODEL / GBK - 1) {   // prefetch kt+1: in flight across MFMA
            const float* ap = aptr + (size_t)(kt + 1) * GBK;
            const float* wp = wptr + (size_t)(kt + 1) * GBK;
#pragma unroll
            for (int c = 0; c < 4; c++) {
                ar[c] = *(const f32x4*)(ap + c * 4);
                wr[c] = *(const f32x4*)(wp + c * 4);
            }
        }

        bf16x8 af[4], bfr[4];
#pragma unroll
        for (int i = 0; i < 4; i++) {
            const int m = wm + i * 16 + l16;
            af[i]  = *(const bf16x8*)&cA[m * GBK + (q4 ^ (m & 3)) * 8];
            const int n = wn + i * 16 + l16;
            bfr[i] = *(const bf16x8*)&cB[n * GBK + (q4 ^ (n & 3)) * 8];
        }
#pragma unroll
        for (int i = 0; i < 4; i++)
#pragma unroll
            for (int j = 0; j < 4; j++)
                acc[i][j] = __builtin_amdgcn_mfma_f32_16x16x32_bf16(af[i], bfr[j], acc[i][j], 0, 0, 0);
    }

    if (z != 2) {
        // normal epilogue: D[row=(lane>>4)*4+r][col=lane&15] per 16x16 tile
#pragma unroll
        for (int j = 0; j < 4; j++) {
            const int col = bn0 + wn + j * 16 + l16;
            const float bj = bias[col];
#pragma unroll
            for (int i = 0; i < 4; i++) {
                const int rowb = bm0 + wm + i * 16 + q4 * 4;
#pragma unroll
                for (int r = 0; r < 4; r++)
                    C[(size_t)(rowb + r) * D_MODEL + col] = (bf16_t)((acc[i][j][r] + bj) * cs);
            }
        }
    } else {
        // V: write transposed per head -> C[(b*1024 + col)*2048 + s'], b64 each
        // s' = key-permuted position within its 32-key chunk (see header).
        const int bb = bm0 >> 11;          // batch (tile never straddles)
        const int sbase = (bm0 & 2047) + wm;
#pragma unroll
        for (int j = 0; j < 4; j++) {
            const int col = bn0 + wn + j * 16 + l16;
            const float bj = bias[col];
            bf16_t* ct = C + ((size_t)bb * 1024 + col) * 2048;
#pragma unroll
            for (int i = 0; i < 4; i++) {
                const int s0 = sbase + i * 16 + q4 * 4;
                // permute: c*32 + g*16 + p*4  ->  c*32 + p*8 + g*4
                const int s0p = (s0 & ~31) | (((s0 >> 2) & 3) << 3) | (((s0 >> 4) & 1) << 2);
                bf16x4 v4;
#pragma unroll
                for (int r = 0; r < 4; r++) v4[r] = (bf16_t)(acc[i][j][r] + bj);
                *(bf16x4*)&ct[s0p] = v4;
            }
        }
    }
}

// ---------------------------------------------------------------------------
// Output GEMM: A bf16 (attention out), W/bias fp32, C fp32 (d_out).
// A: async global_load_lds (double-buffered); W: register prefetch + cvt.
// Single barrier per iteration.
// ---------------------------------------------------------------------------
__global__ __launch_bounds__(256, 3) void gemm_out(
    const bf16_t* __restrict__ A, const float* __restrict__ W,
    const float* __restrict__ bias, float* __restrict__ C)
{
    __align__(16) __shared__ bf16_t sAb[2][128 * GBK];
    __align__(16) __shared__ bf16_t sBb[2][128 * GBK];

    const int t    = threadIdx.x;
    const int lane = t & 63;
    const int w    = t >> 6;
    const int wm   = (w & 1) * 64;
    const int wn   = (w >> 1) * 64;
    const int bm0  = blockIdx.y * 128;
    const int bn0  = blockIdx.x * 128;
    const int q4   = lane >> 4;
    const int l16  = lane & 15;

    const int srow  = t >> 1;
    const int cbase = (t & 1) * 2;
    const float* wptr = &W[(size_t)(bn0 + srow) * D_MODEL + cbase * 8];

    // preamble: async A(0) -> buf0; W(0) -> regs
#pragma unroll
    for (int i = 0; i < 2; i++) {
        const int cid = i * 256 + t;   // 512 bf16 chunks (16B) per A tile
        const int row = cid >> 2;
        const int cl  = cid & 3;
        const int cg  = cl ^ (row & 3);
        async_copy16(&sAb[0][cid * 8], &A[(size_t)(bm0 + row) * D_MODEL + cg * 8]);
    }
    f32x4 wr[4];
#pragma unroll
    for (int c = 0; c < 4; c++) wr[c] = *(const f32x4*)(wptr + c * 4);

    f32x4 acc[4][4];
    const f32x4 zero4 = {0.f, 0.f, 0.f, 0.f};
#pragma unroll
    for (int i = 0; i < 4; i++)
#pragma unroll
        for (int j = 0; j < 4; j++) acc[i][j] = zero4;

    for (int kt = 0; kt < D_MODEL / GBK; ++kt) {
        const int buf = kt & 1;
        bf16x8 wbf[2];
#pragma unroll
        for (int c = 0; c < 4; c++)
#pragma unroll
            for (int j = 0; j < 4; j++)
                wbf[c >> 1][(c & 1) * 4 + j] = (bf16_t)wr[c][j];
#pragma unroll
        for (int hb = 0; hb < 2; hb++) {
            const int slot = (cbase + hb) ^ (srow & 3);
            *(bf16x8*)&sBb[buf][srow * GBK + slot * 8] = wbf[hb];
        }
        __syncthreads();   // drains async A(kt); W writes visible
        if (kt < D_MODEL / GBK - 1) {
            const int k0 = (kt + 1) * GBK;
#pragma unroll
            for (int i = 0; i < 2; i++) {
                const int cid = i * 256 + t;
                const int row = cid >> 2;
                const int cl  = cid & 3;
                const int cg  = cl ^ (row & 3);
                async_copy16(&sAb[buf ^ 1][cid * 8],
                             &A[(size_t)(bm0 + row) * D_MODEL + k0 + cg * 8]);
            }
            const float* wp = wptr + (size_t)(kt + 1) * GBK;
#pragma unroll
            for (int c = 0; c < 4; c++) wr[c] = *(const f32x4*)(wp + c * 4);
        }

        bf16x8 af[4], bfr[4];
#pragma unroll
        for (int i = 0; i < 4; i++) {
            const int m = wm + i * 16 + l16;
            af[i]  = *(const bf16x8*)&sAb[buf][m * GBK + (q4 ^ (m & 3)) * 8];
            const int n = wn + i * 16 + l16;
            bfr[i] = *(const bf16x8*)&sBb[buf][n * GBK + (q4 ^ (n & 3)) * 8];
        }
#pragma unroll
        for (int i = 0; i < 4; i++)
#pragma unroll
            for (int j = 0; j < 4; j++)
                acc[i][j] = __builtin_amdgcn_mfma_f32_16x16x32_bf16(af[i], bfr[j], acc[i][j], 0, 0, 0);
    }

#pragma unroll
    for (int j = 0; j < 4; j++) {
        const int col = bn0 + wn + j * 16 + l16;
        const float bj = bias[col];
#pragma unroll
        for (int i = 0; i < 4; i++) {
            const int rowb = bm0 + wm + i * 16 + q4 * 4;
#pragma unroll
            for (int r = 0; r < 4; r++)
                C[(size_t)(rowb + r) * D_MODEL + col] = acc[i][j][r] + bj;
        }
    }
}

// ---------------------------------------------------------------------------
// Flash attention. grid = (S/128, B*H) linearized+swizzled: each XCD owns 8
// whole heads (their 16 q-blocks), so K/V (4 MB) live in that XCD's L2.
// 256 thr = 4 waves; wave owns 32 q-rows. Swapped QK^T: S^T = mfma(K, Q*0.125)
// -> lane holds P[qrow=l16][keys q4*4+r (+16*ng)]. With kb pre-scaled by
// log2e, softmax is bare exp2. The exp'd scores, packed to bf16 in-register,
// are DIRECTLY the PV A-fragment under a per-32-key permutation that V^T was
// written with (dot-product k-order invariance). No P staging, no sP LDS.
// Row sums: per-lane scalar partials; one xor16+xor32 reduce at the end.
// LDS 32 KB -> 4+ blocks/CU. o aliases q (block-exact disjoint regions).
// ---------------------------------------------------------------------------
__global__ __launch_bounds__(256, 4) void attn_fused(
    const bf16_t* __restrict__ q, const bf16_t* __restrict__ k,
    const bf16_t* __restrict__ vt, bf16_t* o)
{
    __align__(16) __shared__ bf16_t sK[128 * 64];   // [key][dh], 8-chunk swizzle
    __align__(16) __shared__ bf16_t sVt[64 * 128];  // [dh][key-permuted], 16-chunk swizzle

    const int t    = threadIdx.x;
    const int lane = t & 63;
    const int w    = t >> 6;
    // XCD swizzle: assume hw xcd = linear%8; give each XCD 8 contiguous heads.
    const int lin  = blockIdx.x + (int)gridDim.x * blockIdx.y;  // 0..1023
    const int xcd  = lin & 7;
    const int idx  = lin >> 3;                                  // 0..127
    const int head = xcd * 8 + (idx >> 4);
    const int qblk = idx & 15;
    const int b    = head >> 4;
    const int h    = head & 15;
    const size_t base = (size_t)b * S_LEN * D_MODEL + (size_t)h * HEAD_DIM;
    const bf16_t* vth = vt + ((size_t)b * 1024 + h * 64) * 2048;  // [dh][s-perm]
    const int qt0  = qblk * 128;
    const int q4   = lane >> 4;
    const int l16  = lane & 15;

    // q fragments (MFMA B operand: col=l16 -> qrow, k = dh = kk*32+q4*8+j),
    // pre-scaled by 1/sqrt(Dh)=0.125 (exact pow2 in bf16)
    bf16x8 qf[2][2];
#pragma unroll
    for (int mg = 0; mg < 2; mg++)
#pragma unroll
        for (int kk = 0; kk < 2; kk++) {
            bf16x8 tmp = *(const bf16x8*)&q[base + (size_t)(qt0 + w * 32 + mg * 16 + l16) * D_MODEL + kk * 32 + q4 * 8];
#pragma unroll
            for (int j = 0; j < 8; j++) tmp[j] = (bf16_t)((float)tmp[j] * 0.125f);
            qf[mg][kk] = tmp;
        }

    f32x4 oacc[2][4];
    const f32x4 zero4 = {0.f, 0.f, 0.f, 0.f};
#pragma unroll
    for (int mg = 0; mg < 2; mg++)
#pragma unroll
        for (int g = 0; g < 4; g++) oacc[mg][g] = zero4;
    float lsum[2] = {0.f, 0.f};

    for (int kt = 0; kt < S_LEN / 128; ++kt) {
        const int key0 = kt * 128;
        __syncthreads();   // prior tile's sK/sVt reads complete

        // stage K async: 1024 chunks, 8-chunk row swizzle
#pragma unroll
        for (int i = 0; i < 4; i++) {
            const int cid = i * 256 + t;
            const int row = cid >> 3;
            const int cl  = cid & 7;
            const int cg  = cl ^ (row & 7);
            async_copy16(&sK[cid * 8], &k[base + (size_t)(key0 + row) * D_MODEL + cg * 8]);
        }
        // stage V^T async: 64 dh-rows x 128 permuted keys, 16-chunk row swizzle
#pragma unroll
        for (int i = 0; i < 4; i++) {
            const int cid = i * 256 + t;
            const int dh  = cid >> 4;
            const int cl  = cid & 15;
            const int cg  = cl ^ (dh & 15);
            async_copy16(&sVt[cid * 8], &vth[(size_t)dh * 2048 + key0 + cg * 8]);
        }
        __syncthreads();   // staged K/V visible (vmcnt drained)

        // two 64-key halves: QK^T -> exp2 -> in-register P fragments -> PV
#pragma unroll
        for (int hh = 0; hh < 2; hh++) {
            // S^T = K @ (Q*0.125)^T : lane holds S[qrow=l16][key=16*ng+q4*4+r]
            f32x4 sc[2][4];
#pragma unroll
            for (int mg = 0; mg < 2; mg++)
#pragma unroll
                for (int ngl = 0; ngl < 4; ngl++) sc[mg][ngl] = zero4;
#pragma unroll
            for (int kk = 0; kk < 2; kk++)
#pragma unroll
                for (int ngl = 0; ngl < 4; ngl++) {
                    const int key = (hh * 4 + ngl) * 16 + l16;
                    const bf16x8 kf = *(const bf16x8*)&sK[key * 64 + (((kk << 2) + q4) ^ (key & 7)) * 8];
#pragma unroll
                    for (int mg = 0; mg < 2; mg++)
                        sc[mg][ngl] = __builtin_amdgcn_mfma_f32_16x16x32_bf16(kf, qf[mg][kk], sc[mg][ngl], 0, 0, 0);
                }

            // fixed-max softmax (kb carries log2e): p = 2^s, per-lane partials,
            // then pack straight into the PV A-fragment (permuted k-order):
            // element j of chunk cl holds key c*32 + (j>>2)*16 + q4*4 + (j&3).
            bf16x8 pf[2][2];
#pragma unroll
            for (int mg = 0; mg < 2; mg++) {
                float s = 0.f;
#pragma unroll
                for (int ngl = 0; ngl < 4; ngl++)
#pragma unroll
                    for (int r = 0; r < 4; r++) {
                        const float p = exp2f(sc[mg][ngl][r]);
                        sc[mg][ngl][r] = p;
                        s += p;
                    }
                lsum[mg] += s;
#pragma unroll
                for (int cl = 0; cl < 2; cl++) {
                    bf16x8 pv;
#pragma unroll
                    for (int j = 0; j < 8; j++)
                        pv[j] = (bf16_t)sc[mg][cl * 2 + (j >> 2)][j & 3];
                    pf[mg][cl] = pv;
                }
            }

            // PV: V^T already stored in the same permuted k-order
#pragma unroll
            for (int cl = 0; cl < 2; cl++) {
                const int cb = (hh * 2 + cl) * 4;
#pragma unroll
                for (int g = 0; g < 4; g++) {
                    const int dh = g * 16 + l16;
                    const bf16x8 vf = *(const bf16x8*)&sVt[dh * 128 + ((cb + q4) ^ l16) * 8];
#pragma unroll
                    for (int mg = 0; mg < 2; mg++)
                        oacc[mg][g] = __builtin_amdgcn_mfma_f32_16x16x32_bf16(pf[mg][cl], vf, oacc[mg][g], 0, 0, 0);
                }
            }
        }
    }

    // row-sum reduce across the 4 q4-groups (lanes sharing l16), then pull the
    // sum for this lane's output rows (qrow = q4*4+r lives at lane q4*4+r).
    float tsum[2];
#pragma unroll
    for (int mg = 0; mg < 2; mg++) {
        float s = lsum[mg];
        s += __shfl_xor(s, 16, 64);
        s += __shfl_xor(s, 32, 64);
        tsum[mg] = s;
    }
#pragma unroll
    for (int mg = 0; mg < 2; mg++)
#pragma unroll
        for (int r = 0; r < 4; r++) {
            const float inv = 1.0f / __shfl(tsum[mg], q4 * 4 + r, 64);
            const size_t rowoff = base + (size_t)(qt0 + w * 32 + mg * 16 + q4 * 4 + r) * D_MODEL;
#pragma unroll
            for (int g = 0; g < 4; g++)
                o[rowoff + g * 16 + l16] = (bf16_t)(oacc[mg][g][r] * inv);
        }
}

// ---------------------------------------------------------------------------
extern "C" void kernel_launch(void* const* d_in, const int* in_sizes, int n_in,
                              void* d_out, int out_size, void* d_ws, size_t ws_size,
                              hipStream_t stream) {
    const float* Q  = (const float*)d_in[0];
    const float* K  = (const float*)d_in[1];
    const float* V  = (const float*)d_in[2];
    const float* Wq = (const float*)d_in[3];
    const float* bq = (const float*)d_in[4];
    const float* Wk = (const float*)d_in[5];
    const float* bk = (const float*)d_in[6];
    const float* Wv = (const float*)d_in[7];
    const float* bv = (const float*)d_in[8];
    const float* Wo = (const float*)d_in[9];
    const float* bo = (const float*)d_in[10];
    float* out = (float*)d_out;

    // Internal bf16 buffers: qb | vb(transposed+key-permuted per head) in ws;
    // kb (pre-scaled by log2e) parked in d_out. Attention output aliases qb.
    bf16_t* qb = (bf16_t*)d_ws;
    bf16_t* vb = qb + (size_t)M_ROWS * D_MODEL;
    bf16_t* kb = (bf16_t*)d_out;
    bf16_t* ob = qb;

    dim3 blk(256);
    gemm_proj<<<dim3(8, 64, 3), blk, 0, stream>>>(Q, Wq, bq, K, Wk, bk, V, Wv, bv, qb, kb, vb);
    attn_fused<<<dim3(S_LEN / 128, 4 * N_HEADS), blk, 0, stream>>>(qb, kb, vb, ob);
    gemm_out<<<dim3(8, 64), blk, 0, stream>>>(ob, Wo, bo, out);
}

// Round 2
// 449.749 us; speedup vs baseline: 1.1405x; 1.1405x over previous
//
#include <hip/hip_runtime.h>
#include <hip/hip_bf16.h>
#include <stdint.h>
#include <stddef.h>

// ---------------------------------------------------------------------------
// MultiHeadAttention: q/k/v = X @ W.T + b ; flash-attn per head ; out @ Wo.T+bo
// FP32 in/out buffers; bf16 MFMA internally.
// B=4 S=2048 D=1024 H=16 Dh=64 -> M = B*S = 8192
// Round 7: attn restructured. Round-6's launch_bounds(256,4) capped the
// unified VGPR+AGPR file at 128 -> scratch spill (WRITE_SIZE 428 MB). Now:
// 8-wave blocks (QBLK=256, half the K/V passes), launch_bounds(512,3),
// double-buffered K/V with the proven 2-phase counted pipeline (one raw
// s_barrier + vmcnt(0) per tile; stage(t+1) flies under compute(t)).
// In-register P (swapped QK^T + permuted V^T) and log2e-in-kb retained.
// ---------------------------------------------------------------------------

typedef __bf16 bf16_t;
typedef __bf16 bf16x4 __attribute__((ext_vector_type(4)));
typedef __bf16 bf16x8 __attribute__((ext_vector_type(8)));
typedef float f32x4 __attribute__((ext_vector_type(4)));

#define D_MODEL 1024
#define M_ROWS  8192
#define S_LEN   2048
#define N_HEADS 16
#define HEAD_DIM 64
#define GBK 32

__device__ __forceinline__ void async_copy16(void* lds, const void* g) {
    __builtin_amdgcn_global_load_lds(
        (const __attribute__((address_space(1))) void*)g,
        (__attribute__((address_space(3))) void*)lds, 16, 0, 0);
}

// ---------------------------------------------------------------------------
// Projection GEMM: C[m,n] = sum_k A[m,k]*W[n,k] + bias[n]
// A,W,bias fp32; C bf16. 128x128 tile, BK=32, 256 thr (4 waves, 2x2 of 64x64).
// z==1 (K proj): output pre-scaled by log2e (softmax then needs bare exp2).
// z==2 (V proj): output transposed per head [b][dh][s], keys PERMUTED within
// each 32-key chunk: pos = c*32 + p*8 + g*4 + e <- key = c*32 + g*16 + p*4 + e
// (so attn's in-register P fragments match V^T's k-ordering).
// ---------------------------------------------------------------------------
__global__ __launch_bounds__(256, 3) void gemm_proj(
    const float* __restrict__ A0, const float* __restrict__ W0, const float* __restrict__ b0,
    const float* __restrict__ A1, const float* __restrict__ W1, const float* __restrict__ b1,
    const float* __restrict__ A2, const float* __restrict__ W2, const float* __restrict__ b2,
    bf16_t* C0, bf16_t* C1, bf16_t* C2)
{
    const float* A; const float* W; const float* bias; bf16_t* C;
    const int z = blockIdx.z;
    if (z == 0)      { A = A0; W = W0; bias = b0; C = C0; }
    else if (z == 1) { A = A1; W = W1; bias = b1; C = C1; }
    else             { A = A2; W = W2; bias = b2; C = C2; }
    const float cs = (z == 1) ? 1.4426950408889634f : 1.0f;  // log2e into kb

    __align__(16) __shared__ bf16_t sA[2][128 * GBK];   // 8 KB per buf
    __align__(16) __shared__ bf16_t sB[2][128 * GBK];

    const int t    = threadIdx.x;
    const int lane = t & 63;
    const int w    = t >> 6;
    const int wm   = (w & 1) * 64;
    const int wn   = (w >> 1) * 64;
    const int bm0  = blockIdx.y * 128;
    const int bn0  = blockIdx.x * 128;
    const int q4   = lane >> 4;
    const int l16  = lane & 15;

    // staging role: row = t>>1, 16-elem k-half = (t&1)*16 (2 16B chunks)
    const int srow  = t >> 1;
    const int cbase = (t & 1) * 2;
    const float* aptr = &A[(size_t)(bm0 + srow) * D_MODEL + cbase * 8];
    const float* wptr = &W[(size_t)(bn0 + srow) * D_MODEL + cbase * 8];

    f32x4 ar[4], wr[4];
#pragma unroll
    for (int c = 0; c < 4; c++) {
        ar[c] = *(const f32x4*)(aptr + c * 4);
        wr[c] = *(const f32x4*)(wptr + c * 4);
    }

    f32x4 acc[4][4];
    const f32x4 zero4 = {0.f, 0.f, 0.f, 0.f};
#pragma unroll
    for (int i = 0; i < 4; i++)
#pragma unroll
        for (int j = 0; j < 4; j++) acc[i][j] = zero4;

    for (int kt = 0; kt < D_MODEL / GBK; ++kt) {
        bf16_t* cA = sA[kt & 1];
        bf16_t* cB = sB[kt & 1];
        // cvt regs (tile kt) -> swizzled bf16 LDS. chunk c stored at c^(row&3).
        bf16x8 abf[2], wbf[2];
#pragma unroll
        for (int c = 0; c < 4; c++)
#pragma unroll
            for (int j = 0; j < 4; j++) {
                abf[c >> 1][(c & 1) * 4 + j] = (bf16_t)ar[c][j];
                wbf[c >> 1][(c & 1) * 4 + j] = (bf16_t)wr[c][j];
            }
#pragma unroll
        for (int hb = 0; hb < 2; hb++) {
            const int slot = (cbase + hb) ^ (srow & 3);
            *(bf16x8*)&cA[srow * GBK + slot * 8] = abf[hb];
            *(bf16x8*)&cB[srow * GBK + slot * 8] = wbf[hb];
        }
        __syncthreads();   // write(kt) visible; prior-buf reads already done
        if (kt < D_MODEL / GBK - 1) {   // prefetch kt+1: in flight across MFMA
            const float* ap = aptr + (size_t)(kt + 1) * GBK;
            const float* wp = wptr + (size_t)(kt + 1) * GBK;
#pragma unroll
            for (int c = 0; c < 4; c++) {
                ar[c] = *(const f32x4*)(ap + c * 4);
                wr[c] = *(const f32x4*)(wp + c * 4);
            }
        }

        bf16x8 af[4], bfr[4];
#pragma unroll
        for (int i = 0; i < 4; i++) {
            const int m = wm + i * 16 + l16;
            af[i]  = *(const bf16x8*)&cA[m * GBK + (q4 ^ (m & 3)) * 8];
            const int n = wn + i * 16 + l16;
            bfr[i] = *(const bf16x8*)&cB[n * GBK + (q4 ^ (n & 3)) * 8];
        }
#pragma unroll
        for (int i = 0; i < 4; i++)
#pragma unroll
            for (int j = 0; j < 4; j++)
                acc[i][j] = __builtin_amdgcn_mfma_f32_16x16x32_bf16(af[i], bfr[j], acc[i][j], 0, 0, 0);
    }

    if (z != 2) {
        // normal epilogue: D[row=(lane>>4)*4+r][col=lane&15] per 16x16 tile
#pragma unroll
        for (int j = 0; j < 4; j++) {
            const int col = bn0 + wn + j * 16 + l16;
            const float bj = bias[col];
#pragma unroll
            for (int i = 0; i < 4; i++) {
                const int rowb = bm0 + wm + i * 16 + q4 * 4;
#pragma unroll
                for (int r = 0; r < 4; r++)
                    C[(size_t)(rowb + r) * D_MODEL + col] = (bf16_t)((acc[i][j][r] + bj) * cs);
            }
        }
    } else {
        // V: write transposed per head -> C[(b*1024 + col)*2048 + s'], b64 each
        // s' = key-permuted position within its 32-key chunk (see header).
        const int bb = bm0 >> 11;          // batch (tile never straddles)
        const int sbase = (bm0 & 2047) + wm;
#pragma unroll
        for (int j = 0; j < 4; j++) {
            const int col = bn0 + wn + j * 16 + l16;
            const float bj = bias[col];
            bf16_t* ct = C + ((size_t)bb * 1024 + col) * 2048;
#pragma unroll
            for (int i = 0; i < 4; i++) {
                const int s0 = sbase + i * 16 + q4 * 4;
                // permute: c*32 + g*16 + p*4  ->  c*32 + p*8 + g*4
                const int s0p = (s0 & ~31) | (((s0 >> 2) & 3) << 3) | (((s0 >> 4) & 1) << 2);
                bf16x4 v4;
#pragma unroll
                for (int r = 0; r < 4; r++) v4[r] = (bf16_t)(acc[i][j][r] + bj);
                *(bf16x4*)&ct[s0p] = v4;
            }
        }
    }
}

// ---------------------------------------------------------------------------
// Output GEMM: A bf16 (attention out), W/bias fp32, C fp32 (d_out).
// A: async global_load_lds (double-buffered); W: register prefetch + cvt.
// Single barrier per iteration.
// ---------------------------------------------------------------------------
__global__ __launch_bounds__(256, 3) void gemm_out(
    const bf16_t* __restrict__ A, const float* __restrict__ W,
    const float* __restrict__ bias, float* __restrict__ C)
{
    __align__(16) __shared__ bf16_t sAb[2][128 * GBK];
    __align__(16) __shared__ bf16_t sBb[2][128 * GBK];

    const int t    = threadIdx.x;
    const int lane = t & 63;
    const int w    = t >> 6;
    const int wm   = (w & 1) * 64;
    const int wn   = (w >> 1) * 64;
    const int bm0  = blockIdx.y * 128;
    const int bn0  = blockIdx.x * 128;
    const int q4   = lane >> 4;
    const int l16  = lane & 15;

    const int srow  = t >> 1;
    const int cbase = (t & 1) * 2;
    const float* wptr = &W[(size_t)(bn0 + srow) * D_MODEL + cbase * 8];

    // preamble: async A(0) -> buf0; W(0) -> regs
#pragma unroll
    for (int i = 0; i < 2; i++) {
        const int cid = i * 256 + t;   // 512 bf16 chunks (16B) per A tile
        const int row = cid >> 2;
        const int cl  = cid & 3;
        const int cg  = cl ^ (row & 3);
        async_copy16(&sAb[0][cid * 8], &A[(size_t)(bm0 + row) * D_MODEL + cg * 8]);
    }
    f32x4 wr[4];
#pragma unroll
    for (int c = 0; c < 4; c++) wr[c] = *(const f32x4*)(wptr + c * 4);

    f32x4 acc[4][4];
    const f32x4 zero4 = {0.f, 0.f, 0.f, 0.f};
#pragma unroll
    for (int i = 0; i < 4; i++)
#pragma unroll
        for (int j = 0; j < 4; j++) acc[i][j] = zero4;

    for (int kt = 0; kt < D_MODEL / GBK; ++kt) {
        const int buf = kt & 1;
        bf16x8 wbf[2];
#pragma unroll
        for (int c = 0; c < 4; c++)
#pragma unroll
            for (int j = 0; j < 4; j++)
                wbf[c >> 1][(c & 1) * 4 + j] = (bf16_t)wr[c][j];
#pragma unroll
        for (int hb = 0; hb < 2; hb++) {
            const int slot = (cbase + hb) ^ (srow & 3);
            *(bf16x8*)&sBb[buf][srow * GBK + slot * 8] = wbf[hb];
        }
        __syncthreads();   // drains async A(kt); W writes visible
        if (kt < D_MODEL / GBK - 1) {
            const int k0 = (kt + 1) * GBK;
#pragma unroll
            for (int i = 0; i < 2; i++) {
                const int cid = i * 256 + t;
                const int row = cid >> 2;
                const int cl  = cid & 3;
                const int cg  = cl ^ (row & 3);
                async_copy16(&sAb[buf ^ 1][cid * 8],
                             &A[(size_t)(bm0 + row) * D_MODEL + k0 + cg * 8]);
            }
            const float* wp = wptr + (size_t)(kt + 1) * GBK;
#pragma unroll
            for (int c = 0; c < 4; c++) wr[c] = *(const f32x4*)(wp + c * 4);
        }

        bf16x8 af[4], bfr[4];
#pragma unroll
        for (int i = 0; i < 4; i++) {
            const int m = wm + i * 16 + l16;
            af[i]  = *(const bf16x8*)&sAb[buf][m * GBK + (q4 ^ (m & 3)) * 8];
            const int n = wn + i * 16 + l16;
            bfr[i] = *(const bf16x8*)&sBb[buf][n * GBK + (q4 ^ (n & 3)) * 8];
        }
#pragma unroll
        for (int i = 0; i < 4; i++)
#pragma unroll
            for (int j = 0; j < 4; j++)
                acc[i][j] = __builtin_amdgcn_mfma_f32_16x16x32_bf16(af[i], bfr[j], acc[i][j], 0, 0, 0);
    }

#pragma unroll
    for (int j = 0; j < 4; j++) {
        const int col = bn0 + wn + j * 16 + l16;
        const float bj = bias[col];
#pragma unroll
        for (int i = 0; i < 4; i++) {
            const int rowb = bm0 + wm + i * 16 + q4 * 4;
#pragma unroll
            for (int r = 0; r < 4; r++)
                C[(size_t)(rowb + r) * D_MODEL + col] = acc[i][j][r] + bj;
        }
    }
}

// ---------------------------------------------------------------------------
// Flash attention. grid = (B*H=64, S/256=8), 512 thr = 8 waves; wave owns 32
// q-rows (QBLK=256 per block -> half the K/V passes of QBLK=128).
// K and permuted V^T double-buffered in LDS (64 KB), staged via
// global_load_lds with the 2-phase counted pipeline: per tile ONE raw
// s_barrier + s_waitcnt vmcnt(0); stage(t+1) issued before compute(t) so the
// loads fly under 64 MFMAs + softmax. Swapped QK^T (S^T = mfma(K, Q*0.125)):
// lane holds P[qrow=l16][keys q4*4+r (+16*ng)]; kb pre-scaled by log2e so
// softmax is bare exp2; exp'd scores packed in-register ARE the PV A-fragment
// (V^T written with matching per-32-key permutation). No P staging.
// launch_bounds(512,3): 170-reg cap, no spill (round-6 lesson: cap 128
// spilled ~500 MB to scratch). o aliases q (block-exact disjoint regions).
// ---------------------------------------------------------------------------
#define KVT (S_LEN / 128)   // 16 key tiles

__global__ __launch_bounds__(512, 3) void attn_fused(
    const bf16_t* __restrict__ q, const bf16_t* __restrict__ k,
    const bf16_t* __restrict__ vt, bf16_t* o)
{
    __align__(16) __shared__ bf16_t sK[2][128 * 64];   // [key][dh], 8-chunk swizzle
    __align__(16) __shared__ bf16_t sVt[2][64 * 128];  // [dh][key-perm], 16-chunk swizzle

    const int t    = threadIdx.x;
    const int lane = t & 63;
    const int w    = t >> 6;                 // 0..7
    const int head = blockIdx.x;             // 0..63
    const int b    = head >> 4;
    const int h    = head & 15;
    const size_t base = (size_t)b * S_LEN * D_MODEL + (size_t)h * HEAD_DIM;
    const bf16_t* vth = vt + ((size_t)b * 1024 + h * 64) * 2048;  // [dh][s-perm]
    const int qt0  = blockIdx.y * 256;
    const int q4   = lane >> 4;
    const int l16  = lane & 15;

    // q fragments (MFMA B operand: col=l16 -> qrow, k = dh = kk*32+q4*8+j),
    // pre-scaled by 1/sqrt(Dh)=0.125 (exact pow2 in bf16). Loaded BEFORE the
    // first stage so the compiler's q-wait doesn't drain the pipeline.
    bf16x8 qf[2][2];
#pragma unroll
    for (int mg = 0; mg < 2; mg++)
#pragma unroll
        for (int kk = 0; kk < 2; kk++) {
            bf16x8 tmp = *(const bf16x8*)&q[base + (size_t)(qt0 + w * 32 + mg * 16 + l16) * D_MODEL + kk * 32 + q4 * 8];
#pragma unroll
            for (int j = 0; j < 8; j++) tmp[j] = (bf16_t)((float)tmp[j] * 0.125f);
            qf[mg][kk] = tmp;
        }

    f32x4 oacc[2][4];
    const f32x4 zero4 = {0.f, 0.f, 0.f, 0.f};
#pragma unroll
    for (int mg = 0; mg < 2; mg++)
#pragma unroll
        for (int g = 0; g < 4; g++) oacc[mg][g] = zero4;
    float lsum[2] = {0.f, 0.f};

    // ---- stage tile kt into buffer bf (2 K-chunks + 2 V-chunks per thread)
    auto stage = [&](int bf, int kt) {
        const int key0 = kt * 128;
#pragma unroll
        for (int i = 0; i < 2; i++) {
            const int cid = i * 512 + t;           // 1024 16B chunks of K
            const int row = cid >> 3;
            const int cg  = (cid & 7) ^ (row & 7);
            async_copy16(&sK[bf][cid * 8], &k[base + (size_t)(key0 + row) * D_MODEL + cg * 8]);
        }
#pragma unroll
        for (int i = 0; i < 2; i++) {
            const int cid = i * 512 + t;           // 1024 16B chunks of V^T
            const int dh  = cid >> 4;
            const int cg  = (cid & 15) ^ (dh & 15);
            async_copy16(&sVt[bf][cid * 8], &vth[(size_t)dh * 2048 + key0 + cg * 8]);
        }
    };

    // prologue: tile 0 into buf0, drain, publish
    stage(0, 0);
    asm volatile("s_waitcnt vmcnt(0)" ::: "memory");
    __builtin_amdgcn_s_barrier();
    __builtin_amdgcn_sched_barrier(0);

    for (int kt = 0; kt < KVT; ++kt) {
        const int cur = kt & 1;
        if (kt < KVT - 1) stage(cur ^ 1, kt + 1);   // flies under compute

        // two 64-key halves: QK^T -> exp2 -> in-register P fragments -> PV
#pragma unroll
        for (int hh = 0; hh < 2; hh++) {
            // S^T = K @ (Q*0.125)^T : lane holds S[qrow=l16][key=16*ng+q4*4+r]
            f32x4 sc[2][4];
#pragma unroll
            for (int mg = 0; mg < 2; mg++)
#pragma unroll
                for (int ngl = 0; ngl < 4; ngl++) sc[mg][ngl] = zero4;
#pragma unroll
            for (int kk = 0; kk < 2; kk++)
#pragma unroll
                for (int ngl = 0; ngl < 4; ngl++) {
                    const int key = (hh * 4 + ngl) * 16 + l16;
                    const bf16x8 kf = *(const bf16x8*)&sK[cur][key * 64 + (((kk << 2) + q4) ^ (key & 7)) * 8];
#pragma unroll
                    for (int mg = 0; mg < 2; mg++)
                        sc[mg][ngl] = __builtin_amdgcn_mfma_f32_16x16x32_bf16(kf, qf[mg][kk], sc[mg][ngl], 0, 0, 0);
                }

            // fixed-max softmax (kb carries log2e): p = 2^s, per-lane partials,
            // then pack straight into the PV A-fragment (permuted k-order):
            // element j of chunk cl holds key c*32 + (j>>2)*16 + q4*4 + (j&3).
            bf16x8 pf[2][2];
#pragma unroll
            for (int mg = 0; mg < 2; mg++) {
                float s = 0.f;
#pragma unroll
                for (int ngl = 0; ngl < 4; ngl++)
#pragma unroll
                    for (int r = 0; r < 4; r++) {
                        const float p = exp2f(sc[mg][ngl][r]);
                        sc[mg][ngl][r] = p;
                        s += p;
                    }
                lsum[mg] += s;
#pragma unroll
                for (int cl = 0; cl < 2; cl++) {
                    bf16x8 pv;
#pragma unroll
                    for (int j = 0; j < 8; j++)
                        pv[j] = (bf16_t)sc[mg][cl * 2 + (j >> 2)][j & 3];
                    pf[mg][cl] = pv;
                }
            }

            // PV: V^T already stored in the same permuted k-order
#pragma unroll
            for (int cl = 0; cl < 2; cl++) {
                const int cb = (hh * 2 + cl) * 4;
#pragma unroll
                for (int g = 0; g < 4; g++) {
                    const int dh = g * 16 + l16;
                    const bf16x8 vf = *(const bf16x8*)&sVt[cur][dh * 128 + ((cb + q4) ^ l16) * 8];
#pragma unroll
                    for (int mg = 0; mg < 2; mg++)
                        oacc[mg][g] = __builtin_amdgcn_mfma_f32_16x16x32_bf16(pf[mg][cl], vf, oacc[mg][g], 0, 0, 0);
                }
            }
        }

        // end of tile: next-tile loads must be home before anyone reads buf^1,
        // and all waves must be done reading buf[cur] before tile kt+2 refills.
        asm volatile("s_waitcnt vmcnt(0)" ::: "memory");
        __builtin_amdgcn_s_barrier();
        __builtin_amdgcn_sched_barrier(0);
    }

    // row-sum reduce across the 4 q4-groups (lanes sharing l16), then pull the
    // sum for this lane's output rows (qrow = q4*4+r lives at lane q4*4+r).
    float tsum[2];
#pragma unroll
    for (int mg = 0; mg < 2; mg++) {
        float s = lsum[mg];
        s += __shfl_xor(s, 16, 64);
        s += __shfl_xor(s, 32, 64);
        tsum[mg] = s;
    }
#pragma unroll
    for (int mg = 0; mg < 2; mg++)
#pragma unroll
        for (int r = 0; r < 4; r++) {
            const float inv = 1.0f / __shfl(tsum[mg], q4 * 4 + r, 64);
            const size_t rowoff = base + (size_t)(qt0 + w * 32 + mg * 16 + q4 * 4 + r) * D_MODEL;
#pragma unroll
            for (int g = 0; g < 4; g++)
                o[rowoff + g * 16 + l16] = (bf16_t)(oacc[mg][g][r] * inv);
        }
}

// ---------------------------------------------------------------------------
extern "C" void kernel_launch(void* const* d_in, const int* in_sizes, int n_in,
                              void* d_out, int out_size, void* d_ws, size_t ws_size,
                              hipStream_t stream) {
    const float* Q  = (const float*)d_in[0];
    const float* K  = (const float*)d_in[1];
    const float* V  = (const float*)d_in[2];
    const float* Wq = (const float*)d_in[3];
    const float* bq = (const float*)d_in[4];
    const float* Wk = (const float*)d_in[5];
    const float* bk = (const float*)d_in[6];
    const float* Wv = (const float*)d_in[7];
    const float* bv = (const float*)d_in[8];
    const float* Wo = (const float*)d_in[9];
    const float* bo = (const float*)d_in[10];
    float* out = (float*)d_out;

    // Internal bf16 buffers: qb | vb(transposed+key-permuted per head) in ws;
    // kb (pre-scaled by log2e) parked in d_out. Attention output aliases qb.
    bf16_t* qb = (bf16_t*)d_ws;
    bf16_t* vb = qb + (size_t)M_ROWS * D_MODEL;
    bf16_t* kb = (bf16_t*)d_out;
    bf16_t* ob = qb;

    gemm_proj<<<dim3(8, 64, 3), dim3(256), 0, stream>>>(Q, Wq, bq, K, Wk, bk, V, Wv, bv, qb, kb, vb);
    attn_fused<<<dim3(4 * N_HEADS, S_LEN / 256), dim3(512), 0, stream>>>(qb, kb, vb, ob);
    gemm_out<<<dim3(8, 64), dim3(256), 0, stream>>>(ob, Wo, bo, out);
}

// Round 3
// 401.244 us; speedup vs baseline: 1.2784x; 1.1209x over previous
//
#include <hip/hip_runtime.h>
#include <hip/hip_bf16.h>
#include <stdint.h>
#include <stddef.h>

// ---------------------------------------------------------------------------
// MultiHeadAttention: q/k/v = X @ W.T + b ; flash-attn per head ; out @ Wo.T+bo
// FP32 in/out buffers; bf16 MFMA internally.
// B=4 S=2048 D=1024 H=16 Dh=64 -> M = B*S = 8192
// Round 8: gemm_proj/gemm_out attacked (proj was 170us, FETCH 405 MB vs 108
// unique -> cross-XCD A re-fetch + latency-bound register staging).
//  - XCD-chunked block swizzle in both GEMMs (A panel lives in one XCD's L2).
//  - W's pre-converted to bf16 once (parked in d_out above kb / in dead vb),
//    so B operands stage via global_load_lds (linear dest, source swizzle).
//  - proj A: fp32 reg-staged with 2-deep NAMED prefetch regs (consume point
//    is past the next barrier's vmcnt(0) drain -> no mid-iter stall).
//  - gemm_out: both operands async, one barrier/iter, ~zero VALU.
// attn unchanged from round 7 (8-wave QBLK=256, dbuf K/V, in-register P).
// ---------------------------------------------------------------------------

typedef __bf16 bf16_t;
typedef __bf16 bf16x4 __attribute__((ext_vector_type(4)));
typedef __bf16 bf16x8 __attribute__((ext_vector_type(8)));
typedef float f32x4 __attribute__((ext_vector_type(4)));

#define D_MODEL 1024
#define M_ROWS  8192
#define S_LEN   2048
#define N_HEADS 16
#define HEAD_DIM 64
#define GBK 32
#define NT (D_MODEL / GBK)   // 32 k-tiles

__device__ __forceinline__ void async_copy16(void* lds, const void* g) {
    __builtin_amdgcn_global_load_lds(
        (const __attribute__((address_space(1))) void*)g,
        (__attribute__((address_space(3))) void*)lds, 16, 0, 0);
}

// ---------------------------------------------------------------------------
// fp32 -> bf16 conversion (W matrices, 1M elems each). grid (512, nmat).
// ---------------------------------------------------------------------------
__global__ __launch_bounds__(256) void conv_w(
    const float* __restrict__ s0, const float* __restrict__ s1, const float* __restrict__ s2,
    bf16_t* __restrict__ d0, bf16_t* __restrict__ d1, bf16_t* __restrict__ d2)
{
    const float* s; bf16_t* d;
    if (blockIdx.y == 0)      { s = s0; d = d0; }
    else if (blockIdx.y == 1) { s = s1; d = d1; }
    else                      { s = s2; d = d2; }
    const int i = (blockIdx.x * 256 + threadIdx.x) * 8;
    const f32x4 a = *(const f32x4*)(s + i);
    const f32x4 b = *(const f32x4*)(s + i + 4);
    bf16x8 o;
#pragma unroll
    for (int j = 0; j < 4; j++) { o[j] = (bf16_t)a[j]; o[4 + j] = (bf16_t)b[j]; }
    *(bf16x8*)(d + i) = o;
}

// ---------------------------------------------------------------------------
// Projection GEMM: C[m,n] = sum_k A[m,k]*W[n,k] + bias[n]
// A fp32 (reg-staged, 2-deep named prefetch); W bf16 (global_load_lds);
// bias fp32; C bf16. 128x128 tile, BK=32, 256 thr (4 waves, 2x2 of 64x64).
// XCD-chunked swizzle: 1536 blocks -> each XCD gets 192 consecutive work
// items (bn fastest) so an A panel is fetched once per XCD and L2-served.
// z==1 (K proj): output pre-scaled by log2e. z==2 (V proj): transposed per
// head [b][dh][s] with per-32-key permutation (attn's PV k-ordering).
// ---------------------------------------------------------------------------
__global__ __launch_bounds__(256, 3) void gemm_proj(
    const float* __restrict__ A0, const bf16_t* __restrict__ W0, const float* __restrict__ b0,
    const float* __restrict__ A1, const bf16_t* __restrict__ W1, const float* __restrict__ b1,
    const float* __restrict__ A2, const bf16_t* __restrict__ W2, const float* __restrict__ b2,
    bf16_t* C0, bf16_t* C1, bf16_t* C2)
{
    // XCD swizzle: hw assigns linear blocks round-robin to 8 XCDs.
    const int lin = blockIdx.x + ((int)blockIdx.y << 3) + ((int)blockIdx.z << 9);
    const int nl  = (lin & 7) * 192 + (lin >> 3);          // bijective, 1536%8==0
    const int z   = nl >> 9;
    const int rem = nl & 511;
    const int bm0 = (rem >> 3) * 128;
    const int bn0 = (rem & 7) * 128;

    const float* A; const bf16_t* W; const float* bias; bf16_t* C;
    if (z == 0)      { A = A0; W = W0; bias = b0; C = C0; }
    else if (z == 1) { A = A1; W = W1; bias = b1; C = C1; }
    else             { A = A2; W = W2; bias = b2; C = C2; }
    const float cs = (z == 1) ? 1.4426950408889634f : 1.0f;  // log2e into kb

    __align__(16) __shared__ bf16_t sA[2][128 * 36];   // padded: conflict-free reads
    __align__(16) __shared__ bf16_t sW[2][128 * GBK];  // linear: async dest

    const int t    = threadIdx.x;
    const int lane = t & 63;
    const int w    = t >> 6;
    const int wm   = (w & 1) * 64;
    const int wn   = (w >> 1) * 64;
    const int q4   = lane >> 4;
    const int l16  = lane & 15;

    // A staging role: row = t>>1, 16-elem k-half = (t&1)*16
    const int srow  = t >> 1;
    const int cbase = (t & 1) * 2;
    const float* aptr = &A[(size_t)(bm0 + srow) * D_MODEL + cbase * 8];

    // W staging: 512 16B chunks; source-side XOR swizzle, linear LDS dest
    auto stageW = [&](int buf, int kt) {
#pragma unroll
        for (int i = 0; i < 2; i++) {
            const int cid = i * 256 + t;
            const int row = cid >> 2;
            const int cg  = (cid & 3) ^ (row & 3);
            async_copy16(&sW[buf][cid * 8],
                         &W[(size_t)(bn0 + row) * D_MODEL + kt * GBK + cg * 8]);
        }
    };

    // preamble: A(0)->arA, A(1)->arB, async W(0)
    f32x4 arA[4], arB[4];
#pragma unroll
    for (int c = 0; c < 4; c++) {
        arA[c] = *(const f32x4*)(aptr + c * 4);
        arB[c] = *(const f32x4*)(aptr + GBK + c * 4);
    }
    stageW(0, 0);

    f32x4 acc[4][4];
    const f32x4 zero4 = {0.f, 0.f, 0.f, 0.f};
#pragma unroll
    for (int i = 0; i < 4; i++)
#pragma unroll
        for (int j = 0; j < 4; j++) acc[i][j] = zero4;

    // one k-step; buf is a literal at each call site (constant-folds), ar is a
    // NAMED register set (no runtime-indexed reg arrays -> no scratch).
    auto body = [&](int kt, int buf, f32x4 (&ar)[4]) {
        // cvt A(kt) regs -> swizzled padded LDS
        bf16x8 abf[2];
#pragma unroll
        for (int c = 0; c < 4; c++)
#pragma unroll
            for (int j = 0; j < 4; j++)
                abf[c >> 1][(c & 1) * 4 + j] = (bf16_t)ar[c][j];
#pragma unroll
        for (int hb = 0; hb < 2; hb++) {
            const int slot = (cbase + hb) ^ (srow & 3);
            *(bf16x8*)&sA[buf][srow * 36 + slot * 8] = abf[hb];
        }
        __syncthreads();   // drains async W(kt); publishes A writes
        if (kt + 2 < NT) {             // 2-deep A prefetch into the slot just consumed
            const float* ap = aptr + (size_t)(kt + 2) * GBK;
#pragma unroll
            for (int c = 0; c < 4; c++) ar[c] = *(const f32x4*)(ap + c * 4);
        }
        if (kt + 1 < NT) stageW(buf ^ 1, kt + 1);   // flies under MFMAs

        bf16x8 af[4], bfr[4];
#pragma unroll
        for (int i = 0; i < 4; i++) {
            const int m = wm + i * 16 + l16;
            af[i]  = *(const bf16x8*)&sA[buf][m * 36 + (q4 ^ (m & 3)) * 8];
            const int n = wn + i * 16 + l16;
            bfr[i] = *(const bf16x8*)&sW[buf][n * GBK + (q4 ^ (n & 3)) * 8];
        }
#pragma unroll
        for (int i = 0; i < 4; i++)
#pragma unroll
            for (int j = 0; j < 4; j++)
                acc[i][j] = __builtin_amdgcn_mfma_f32_16x16x32_bf16(af[i], bfr[j], acc[i][j], 0, 0, 0);
    };

    for (int kt = 0; kt < NT; kt += 2) {
        body(kt,     0, arA);
        body(kt + 1, 1, arB);
    }

    if (z != 2) {
        // normal epilogue: D[row=(lane>>4)*4+r][col=lane&15] per 16x16 tile
#pragma unroll
        for (int j = 0; j < 4; j++) {
            const int col = bn0 + wn + j * 16 + l16;
            const float bj = bias[col];
#pragma unroll
            for (int i = 0; i < 4; i++) {
                const int rowb = bm0 + wm + i * 16 + q4 * 4;
#pragma unroll
                for (int r = 0; r < 4; r++)
                    C[(size_t)(rowb + r) * D_MODEL + col] = (bf16_t)((acc[i][j][r] + bj) * cs);
            }
        }
    } else {
        // V: write transposed per head -> C[(b*1024 + col)*2048 + s'], b64 each
        // s' = key-permuted position within its 32-key chunk.
        const int bb = bm0 >> 11;          // batch (tile never straddles)
        const int sbase = (bm0 & 2047) + wm;
#pragma unroll
        for (int j = 0; j < 4; j++) {
            const int col = bn0 + wn + j * 16 + l16;
            const float bj = bias[col];
            bf16_t* ct = C + ((size_t)bb * 1024 + col) * 2048;
#pragma unroll
            for (int i = 0; i < 4; i++) {
                const int s0 = sbase + i * 16 + q4 * 4;
                // permute: c*32 + g*16 + p*4  ->  c*32 + p*8 + g*4
                const int s0p = (s0 & ~31) | (((s0 >> 2) & 3) << 3) | (((s0 >> 4) & 1) << 2);
                bf16x4 v4;
#pragma unroll
                for (int r = 0; r < 4; r++) v4[r] = (bf16_t)(acc[i][j][r] + bj);
                *(bf16x4*)&ct[s0p] = v4;
            }
        }
    }
}

// ---------------------------------------------------------------------------
// Output GEMM: A bf16 (attention out), W bf16 (pre-converted Wo), bias fp32,
// C fp32 (d_out). BOTH operands via global_load_lds, double-buffered, one
// barrier per iteration, XCD-chunked swizzle. Near-zero main-loop VALU.
// ---------------------------------------------------------------------------
__global__ __launch_bounds__(256, 3) void gemm_out(
    const bf16_t* __restrict__ A, const bf16_t* __restrict__ W,
    const float* __restrict__ bias, float* __restrict__ C)
{
    const int lin = blockIdx.x + ((int)blockIdx.y << 3);
    const int nl  = (lin & 7) * 64 + (lin >> 3);           // bijective, 512%8==0
    const int bm0 = (nl >> 3) * 128;
    const int bn0 = (nl & 7) * 128;

    __align__(16) __shared__ bf16_t sA[2][128 * GBK];
    __align__(16) __shared__ bf16_t sW[2][128 * GBK];

    const int t    = threadIdx.x;
    const int lane = t & 63;
    const int w    = t >> 6;
    const int wm   = (w & 1) * 64;
    const int wn   = (w >> 1) * 64;
    const int q4   = lane >> 4;
    const int l16  = lane & 15;

    auto stage = [&](int buf, int kt) {
#pragma unroll
        for (int i = 0; i < 2; i++) {
            const int cid = i * 256 + t;
            const int row = cid >> 2;
            const int cg  = (cid & 3) ^ (row & 3);
            async_copy16(&sA[buf][cid * 8],
                         &A[(size_t)(bm0 + row) * D_MODEL + kt * GBK + cg * 8]);
            async_copy16(&sW[buf][cid * 8],
                         &W[(size_t)(bn0 + row) * D_MODEL + kt * GBK + cg * 8]);
        }
    };

    stage(0, 0);

    f32x4 acc[4][4];
    const f32x4 zero4 = {0.f, 0.f, 0.f, 0.f};
#pragma unroll
    for (int i = 0; i < 4; i++)
#pragma unroll
        for (int j = 0; j < 4; j++) acc[i][j] = zero4;

    for (int kt = 0; kt < NT; ++kt) {
        const int buf = kt & 1;
        __syncthreads();   // drains async(kt) (issued last iter / preamble)
        if (kt + 1 < NT) stage(buf ^ 1, kt + 1);   // flies under MFMAs

        bf16x8 af[4], bfr[4];
#pragma unroll
        for (int i = 0; i < 4; i++) {
            const int m = wm + i * 16 + l16;
            af[i]  = *(const bf16x8*)&sA[buf][m * GBK + (q4 ^ (m & 3)) * 8];
            const int n = wn + i * 16 + l16;
            bfr[i] = *(const bf16x8*)&sW[buf][n * GBK + (q4 ^ (n & 3)) * 8];
        }
#pragma unroll
        for (int i = 0; i < 4; i++)
#pragma unroll
            for (int j = 0; j < 4; j++)
                acc[i][j] = __builtin_amdgcn_mfma_f32_16x16x32_bf16(af[i], bfr[j], acc[i][j], 0, 0, 0);
    }

#pragma unroll
    for (int j = 0; j < 4; j++) {
        const int col = bn0 + wn + j * 16 + l16;
        const float bj = bias[col];
#pragma unroll
        for (int i = 0; i < 4; i++) {
            const int rowb = bm0 + wm + i * 16 + q4 * 4;
#pragma unroll
            for (int r = 0; r < 4; r++)
                C[(size_t)(rowb + r) * D_MODEL + col] = acc[i][j][r] + bj;
        }
    }
}

// ---------------------------------------------------------------------------
// Flash attention (unchanged from round 7). grid = (B*H=64, S/256=8),
// 512 thr = 8 waves; wave owns 32 q-rows. Double-buffered K / permuted V^T,
// one raw s_barrier + vmcnt(0) per tile, stage(t+1) under compute(t).
// Swapped QK^T + in-register P; kb pre-scaled by log2e -> bare exp2.
// ---------------------------------------------------------------------------
#define KVT (S_LEN / 128)   // 16 key tiles

__global__ __launch_bounds__(512, 3) void attn_fused(
    const bf16_t* __restrict__ q, const bf16_t* __restrict__ k,
    const bf16_t* __restrict__ vt, bf16_t* o)
{
    __align__(16) __shared__ bf16_t sK[2][128 * 64];   // [key][dh], 8-chunk swizzle
    __align__(16) __shared__ bf16_t sVt[2][64 * 128];  // [dh][key-perm], 16-chunk swizzle

    const int t    = threadIdx.x;
    const int lane = t & 63;
    const int w    = t >> 6;                 // 0..7
    const int head = blockIdx.x;             // 0..63
    const int b    = head >> 4;
    const int h    = head & 15;
    const size_t base = (size_t)b * S_LEN * D_MODEL + (size_t)h * HEAD_DIM;
    const bf16_t* vth = vt + ((size_t)b * 1024 + h * 64) * 2048;  // [dh][s-perm]
    const int qt0  = blockIdx.y * 256;
    const int q4   = lane >> 4;
    const int l16  = lane & 15;

    bf16x8 qf[2][2];
#pragma unroll
    for (int mg = 0; mg < 2; mg++)
#pragma unroll
        for (int kk = 0; kk < 2; kk++) {
            bf16x8 tmp = *(const bf16x8*)&q[base + (size_t)(qt0 + w * 32 + mg * 16 + l16) * D_MODEL + kk * 32 + q4 * 8];
#pragma unroll
            for (int j = 0; j < 8; j++) tmp[j] = (bf16_t)((float)tmp[j] * 0.125f);
            qf[mg][kk] = tmp;
        }

    f32x4 oacc[2][4];
    const f32x4 zero4 = {0.f, 0.f, 0.f, 0.f};
#pragma unroll
    for (int mg = 0; mg < 2; mg++)
#pragma unroll
        for (int g = 0; g < 4; g++) oacc[mg][g] = zero4;
    float lsum[2] = {0.f, 0.f};

    auto stage = [&](int bf, int kt) {
        const int key0 = kt * 128;
#pragma unroll
        for (int i = 0; i < 2; i++) {
            const int cid = i * 512 + t;           // 1024 16B chunks of K
            const int row = cid >> 3;
            const int cg  = (cid & 7) ^ (row & 7);
            async_copy16(&sK[bf][cid * 8], &k[base + (size_t)(key0 + row) * D_MODEL + cg * 8]);
        }
#pragma unroll
        for (int i = 0; i < 2; i++) {
            const int cid = i * 512 + t;           // 1024 16B chunks of V^T
            const int dh  = cid >> 4;
            const int cg  = (cid & 15) ^ (dh & 15);
            async_copy16(&sVt[bf][cid * 8], &vth[(size_t)dh * 2048 + key0 + cg * 8]);
        }
    };

    stage(0, 0);
    asm volatile("s_waitcnt vmcnt(0)" ::: "memory");
    __builtin_amdgcn_s_barrier();
    __builtin_amdgcn_sched_barrier(0);

    for (int kt = 0; kt < KVT; ++kt) {
        const int cur = kt & 1;
        if (kt < KVT - 1) stage(cur ^ 1, kt + 1);   // flies under compute

#pragma unroll
        for (int hh = 0; hh < 2; hh++) {
            f32x4 sc[2][4];
#pragma unroll
            for (int mg = 0; mg < 2; mg++)
#pragma unroll
                for (int ngl = 0; ngl < 4; ngl++) sc[mg][ngl] = zero4;
#pragma unroll
            for (int kk = 0; kk < 2; kk++)
#pragma unroll
                for (int ngl = 0; ngl < 4; ngl++) {
                    const int key = (hh * 4 + ngl) * 16 + l16;
                    const bf16x8 kf = *(const bf16x8*)&sK[cur][key * 64 + (((kk << 2) + q4) ^ (key & 7)) * 8];
#pragma unroll
                    for (int mg = 0; mg < 2; mg++)
                        sc[mg][ngl] = __builtin_amdgcn_mfma_f32_16x16x32_bf16(kf, qf[mg][kk], sc[mg][ngl], 0, 0, 0);
                }

            bf16x8 pf[2][2];
#pragma unroll
            for (int mg = 0; mg < 2; mg++) {
                float s = 0.f;
#pragma unroll
                for (int ngl = 0; ngl < 4; ngl++)
#pragma unroll
                    for (int r = 0; r < 4; r++) {
                        const float p = exp2f(sc[mg][ngl][r]);
                        sc[mg][ngl][r] = p;
                        s += p;
                    }
                lsum[mg] += s;
#pragma unroll
                for (int cl = 0; cl < 2; cl++) {
                    bf16x8 pv;
#pragma unroll
                    for (int j = 0; j < 8; j++)
                        pv[j] = (bf16_t)sc[mg][cl * 2 + (j >> 2)][j & 3];
                    pf[mg][cl] = pv;
                }
            }

#pragma unroll
            for (int cl = 0; cl < 2; cl++) {
                const int cb = (hh * 2 + cl) * 4;
#pragma unroll
                for (int g = 0; g < 4; g++) {
                    const int dh = g * 16 + l16;
                    const bf16x8 vf = *(const bf16x8*)&sVt[cur][dh * 128 + ((cb + q4) ^ l16) * 8];
#pragma unroll
                    for (int mg = 0; mg < 2; mg++)
                        oacc[mg][g] = __builtin_amdgcn_mfma_f32_16x16x32_bf16(pf[mg][cl], vf, oacc[mg][g], 0, 0, 0);
                }
            }
        }

        asm volatile("s_waitcnt vmcnt(0)" ::: "memory");
        __builtin_amdgcn_s_barrier();
        __builtin_amdgcn_sched_barrier(0);
    }

    float tsum[2];
#pragma unroll
    for (int mg = 0; mg < 2; mg++) {
        float s = lsum[mg];
        s += __shfl_xor(s, 16, 64);
        s += __shfl_xor(s, 32, 64);
        tsum[mg] = s;
    }
#pragma unroll
    for (int mg = 0; mg < 2; mg++)
#pragma unroll
        for (int r = 0; r < 4; r++) {
            const float inv = 1.0f / __shfl(tsum[mg], q4 * 4 + r, 64);
            const size_t rowoff = base + (size_t)(qt0 + w * 32 + mg * 16 + q4 * 4 + r) * D_MODEL;
#pragma unroll
            for (int g = 0; g < 4; g++)
                o[rowoff + g * 16 + l16] = (bf16_t)(oacc[mg][g][r] * inv);
        }
}

// ---------------------------------------------------------------------------
// Buffer plan (ws = 33.55 MB, d_out = 32 MiB fp32 output):
//   ws:    qb [0,16.78MB) | vb [16.78,33.55MB)
//   d_out: kb (bf16) [0,16MiB) | Wq/Wk/Wv bf16 [16,22.3MiB)
//   Wo-bf16 -> vb region (dead after attn). ob aliases qb.
// Order: convW(q,k,v) -> proj -> attn -> convW(o) -> out.
// ---------------------------------------------------------------------------
extern "C" void kernel_launch(void* const* d_in, const int* in_sizes, int n_in,
                              void* d_out, int out_size, void* d_ws, size_t ws_size,
                              hipStream_t stream) {
    const float* Q  = (const float*)d_in[0];
    const float* K  = (const float*)d_in[1];
    const float* V  = (const float*)d_in[2];
    const float* Wq = (const float*)d_in[3];
    const float* bq = (const float*)d_in[4];
    const float* Wk = (const float*)d_in[5];
    const float* bk = (const float*)d_in[6];
    const float* Wv = (const float*)d_in[7];
    const float* bv = (const float*)d_in[8];
    const float* Wo = (const float*)d_in[9];
    const float* bo = (const float*)d_in[10];
    float* out = (float*)d_out;

    bf16_t* qb  = (bf16_t*)d_ws;
    bf16_t* vb  = qb + (size_t)M_ROWS * D_MODEL;
    bf16_t* kb  = (bf16_t*)d_out;
    bf16_t* wqb = kb + (size_t)M_ROWS * D_MODEL;     // d_out + 16 MiB
    bf16_t* wkb = wqb + (size_t)D_MODEL * D_MODEL;
    bf16_t* wvb = wkb + (size_t)D_MODEL * D_MODEL;
    bf16_t* wob = vb;                                 // vb dead after attn
    bf16_t* ob  = qb;

    conv_w<<<dim3(512, 3), dim3(256), 0, stream>>>(Wq, Wk, Wv, wqb, wkb, wvb);
    gemm_proj<<<dim3(8, 64, 3), dim3(256), 0, stream>>>(Q, wqb, bq, K, wkb, bk, V, wvb, bv, qb, kb, vb);
    attn_fused<<<dim3(4 * N_HEADS, S_LEN / 256), dim3(512), 0, stream>>>(qb, kb, vb, ob);
    conv_w<<<dim3(512, 1), dim3(256), 0, stream>>>(Wo, Wo, Wo, wob, wob, wob);
    gemm_out<<<dim3(8, 64), dim3(256), 0, stream>>>(ob, wob, bo, out);
}

// Round 4
// 375.946 us; speedup vs baseline: 1.3644x; 1.0673x over previous
//
#include <hip/hip_runtime.h>
#include <hip/hip_bf16.h>
#include <stdint.h>
#include <stddef.h>

// ---------------------------------------------------------------------------
// MultiHeadAttention: q/k/v = X @ W.T + b ; flash-attn per head ; out @ Wo.T+bo
// FP32 in/out buffers; bf16 MFMA internally.
// B=4 S=2048 D=1024 H=16 Dh=64 -> M = B*S = 8192
// Round 9: attn VALU slash (was VALUBusy 49% vs MfmaUtil 19.5%):
//  - QK^T first k-slice reads the shared zero4 quad as MFMA C (no 64 movs/tile)
//  - row sums via ones-MFMA (kills 64 v_add/tile AND the final shuffle reduce;
//    output layout row=q4*4+r lands sums on the storing lanes directly)
//  - P pack via v_cvt_pk_bf16_f32 (8 packs/fragment-pair vs 64 scalar casts)
//  - 0.125 q-scale folded into Q projection epilogue (exact pow2)
//  - s_setprio(1) around MFMA clusters (T5)
// GEMMs unchanged from round 8 (XCD swizzle, bf16 W via global_load_lds).
// ---------------------------------------------------------------------------

typedef __bf16 bf16_t;
typedef __bf16 bf16x4 __attribute__((ext_vector_type(4)));
typedef __bf16 bf16x8 __attribute__((ext_vector_type(8)));
typedef float f32x4 __attribute__((ext_vector_type(4)));

#define D_MODEL 1024
#define M_ROWS  8192
#define S_LEN   2048
#define N_HEADS 16
#define HEAD_DIM 64
#define GBK 32
#define NT (D_MODEL / GBK)   // 32 k-tiles

__device__ __forceinline__ void async_copy16(void* lds, const void* g) {
    __builtin_amdgcn_global_load_lds(
        (const __attribute__((address_space(1))) void*)g,
        (__attribute__((address_space(3))) void*)lds, 16, 0, 0);
}

__device__ __forceinline__ uint32_t cvt_pk_bf16(float lo, float hi) {
    uint32_t r;
    asm("v_cvt_pk_bf16_f32 %0, %1, %2" : "=v"(r) : "v"(lo), "v"(hi));
    return r;
}

// ---------------------------------------------------------------------------
// fp32 -> bf16 conversion (W matrices, 1M elems each). grid (512, nmat).
// ---------------------------------------------------------------------------
__global__ __launch_bounds__(256) void conv_w(
    const float* __restrict__ s0, const float* __restrict__ s1, const float* __restrict__ s2,
    bf16_t* __restrict__ d0, bf16_t* __restrict__ d1, bf16_t* __restrict__ d2)
{
    const float* s; bf16_t* d;
    if (blockIdx.y == 0)      { s = s0; d = d0; }
    else if (blockIdx.y == 1) { s = s1; d = d1; }
    else                      { s = s2; d = d2; }
    const int i = (blockIdx.x * 256 + threadIdx.x) * 8;
    const f32x4 a = *(const f32x4*)(s + i);
    const f32x4 b = *(const f32x4*)(s + i + 4);
    bf16x8 o;
#pragma unroll
    for (int j = 0; j < 4; j++) { o[j] = (bf16_t)a[j]; o[4 + j] = (bf16_t)b[j]; }
    *(bf16x8*)(d + i) = o;
}

// ---------------------------------------------------------------------------
// Projection GEMM: C[m,n] = sum_k A[m,k]*W[n,k] + bias[n]
// A fp32 (reg-staged, 2-deep named prefetch); W bf16 (global_load_lds);
// bias fp32; C bf16. 128x128 tile, BK=32, 256 thr (4 waves, 2x2 of 64x64).
// XCD-chunked swizzle (1536 blocks, 192/XCD, bn fastest: A panel L2-resident).
// z==0 (Q): output scaled by 0.125 (1/sqrt(Dh), exact pow2 -> attn loads raw).
// z==1 (K): output scaled by log2e (softmax = bare exp2).
// z==2 (V): transposed per head [b][dh][s] with per-32-key permutation.
// ---------------------------------------------------------------------------
__global__ __launch_bounds__(256, 3) void gemm_proj(
    const float* __restrict__ A0, const bf16_t* __restrict__ W0, const float* __restrict__ b0,
    const float* __restrict__ A1, const bf16_t* __restrict__ W1, const float* __restrict__ b1,
    const float* __restrict__ A2, const bf16_t* __restrict__ W2, const float* __restrict__ b2,
    bf16_t* C0, bf16_t* C1, bf16_t* C2)
{
    const int lin = blockIdx.x + ((int)blockIdx.y << 3) + ((int)blockIdx.z << 9);
    const int nl  = (lin & 7) * 192 + (lin >> 3);          // bijective, 1536%8==0
    const int z   = nl >> 9;
    const int rem = nl & 511;
    const int bm0 = (rem >> 3) * 128;
    const int bn0 = (rem & 7) * 128;

    const float* A; const bf16_t* W; const float* bias; bf16_t* C;
    if (z == 0)      { A = A0; W = W0; bias = b0; C = C0; }
    else if (z == 1) { A = A1; W = W1; bias = b1; C = C1; }
    else             { A = A2; W = W2; bias = b2; C = C2; }
    const float cs = (z == 0) ? 0.125f : (z == 1) ? 1.4426950408889634f : 1.0f;

    __align__(16) __shared__ bf16_t sA[2][128 * 36];   // padded: conflict-free reads
    __align__(16) __shared__ bf16_t sW[2][128 * GBK];  // linear: async dest

    const int t    = threadIdx.x;
    const int lane = t & 63;
    const int w    = t >> 6;
    const int wm   = (w & 1) * 64;
    const int wn   = (w >> 1) * 64;
    const int q4   = lane >> 4;
    const int l16  = lane & 15;

    const int srow  = t >> 1;
    const int cbase = (t & 1) * 2;
    const float* aptr = &A[(size_t)(bm0 + srow) * D_MODEL + cbase * 8];

    auto stageW = [&](int buf, int kt) {
#pragma unroll
        for (int i = 0; i < 2; i++) {
            const int cid = i * 256 + t;
            const int row = cid >> 2;
            const int cg  = (cid & 3) ^ (row & 3);
            async_copy16(&sW[buf][cid * 8],
                         &W[(size_t)(bn0 + row) * D_MODEL + kt * GBK + cg * 8]);
        }
    };

    f32x4 arA[4], arB[4];
#pragma unroll
    for (int c = 0; c < 4; c++) {
        arA[c] = *(const f32x4*)(aptr + c * 4);
        arB[c] = *(const f32x4*)(aptr + GBK + c * 4);
    }
    stageW(0, 0);

    f32x4 acc[4][4];
    const f32x4 zero4 = {0.f, 0.f, 0.f, 0.f};
#pragma unroll
    for (int i = 0; i < 4; i++)
#pragma unroll
        for (int j = 0; j < 4; j++) acc[i][j] = zero4;

    auto body = [&](int kt, int buf, f32x4 (&ar)[4]) {
        bf16x8 abf[2];
#pragma unroll
        for (int c = 0; c < 4; c++)
#pragma unroll
            for (int j = 0; j < 4; j++)
                abf[c >> 1][(c & 1) * 4 + j] = (bf16_t)ar[c][j];
#pragma unroll
        for (int hb = 0; hb < 2; hb++) {
            const int slot = (cbase + hb) ^ (srow & 3);
            *(bf16x8*)&sA[buf][srow * 36 + slot * 8] = abf[hb];
        }
        __syncthreads();   // drains async W(kt); publishes A writes
        if (kt + 2 < NT) {
            const float* ap = aptr + (size_t)(kt + 2) * GBK;
#pragma unroll
            for (int c = 0; c < 4; c++) ar[c] = *(const f32x4*)(ap + c * 4);
        }
        if (kt + 1 < NT) stageW(buf ^ 1, kt + 1);

        bf16x8 af[4], bfr[4];
#pragma unroll
        for (int i = 0; i < 4; i++) {
            const int m = wm + i * 16 + l16;
            af[i]  = *(const bf16x8*)&sA[buf][m * 36 + (q4 ^ (m & 3)) * 8];
            const int n = wn + i * 16 + l16;
            bfr[i] = *(const bf16x8*)&sW[buf][n * GBK + (q4 ^ (n & 3)) * 8];
        }
#pragma unroll
        for (int i = 0; i < 4; i++)
#pragma unroll
            for (int j = 0; j < 4; j++)
                acc[i][j] = __builtin_amdgcn_mfma_f32_16x16x32_bf16(af[i], bfr[j], acc[i][j], 0, 0, 0);
    };

    for (int kt = 0; kt < NT; kt += 2) {
        body(kt,     0, arA);
        body(kt + 1, 1, arB);
    }

    if (z != 2) {
#pragma unroll
        for (int j = 0; j < 4; j++) {
            const int col = bn0 + wn + j * 16 + l16;
            const float bj = bias[col];
#pragma unroll
            for (int i = 0; i < 4; i++) {
                const int rowb = bm0 + wm + i * 16 + q4 * 4;
#pragma unroll
                for (int r = 0; r < 4; r++)
                    C[(size_t)(rowb + r) * D_MODEL + col] = (bf16_t)((acc[i][j][r] + bj) * cs);
            }
        }
    } else {
        const int bb = bm0 >> 11;          // batch (tile never straddles)
        const int sbase = (bm0 & 2047) + wm;
#pragma unroll
        for (int j = 0; j < 4; j++) {
            const int col = bn0 + wn + j * 16 + l16;
            const float bj = bias[col];
            bf16_t* ct = C + ((size_t)bb * 1024 + col) * 2048;
#pragma unroll
            for (int i = 0; i < 4; i++) {
                const int s0 = sbase + i * 16 + q4 * 4;
                // permute: c*32 + g*16 + p*4  ->  c*32 + p*8 + g*4
                const int s0p = (s0 & ~31) | (((s0 >> 2) & 3) << 3) | (((s0 >> 4) & 1) << 2);
                bf16x4 v4;
#pragma unroll
                for (int r = 0; r < 4; r++) v4[r] = (bf16_t)(acc[i][j][r] + bj);
                *(bf16x4*)&ct[s0p] = v4;
            }
        }
    }
}

// ---------------------------------------------------------------------------
// Output GEMM: A bf16 (attention out), W bf16 (pre-converted Wo), bias fp32,
// C fp32 (d_out). BOTH operands via global_load_lds, double-buffered, one
// barrier per iteration, XCD-chunked swizzle.
// ---------------------------------------------------------------------------
__global__ __launch_bounds__(256, 3) void gemm_out(
    const bf16_t* __restrict__ A, const bf16_t* __restrict__ W,
    const float* __restrict__ bias, float* __restrict__ C)
{
    const int lin = blockIdx.x + ((int)blockIdx.y << 3);
    const int nl  = (lin & 7) * 64 + (lin >> 3);           // bijective, 512%8==0
    const int bm0 = (nl >> 3) * 128;
    const int bn0 = (nl & 7) * 128;

    __align__(16) __shared__ bf16_t sA[2][128 * GBK];
    __align__(16) __shared__ bf16_t sW[2][128 * GBK];

    const int t    = threadIdx.x;
    const int lane = t & 63;
    const int w    = t >> 6;
    const int wm   = (w & 1) * 64;
    const int wn   = (w >> 1) * 64;
    const int q4   = lane >> 4;
    const int l16  = lane & 15;

    auto stage = [&](int buf, int kt) {
#pragma unroll
        for (int i = 0; i < 2; i++) {
            const int cid = i * 256 + t;
            const int row = cid >> 2;
            const int cg  = (cid & 3) ^ (row & 3);
            async_copy16(&sA[buf][cid * 8],
                         &A[(size_t)(bm0 + row) * D_MODEL + kt * GBK + cg * 8]);
            async_copy16(&sW[buf][cid * 8],
                         &W[(size_t)(bn0 + row) * D_MODEL + kt * GBK + cg * 8]);
        }
    };

    stage(0, 0);

    f32x4 acc[4][4];
    const f32x4 zero4 = {0.f, 0.f, 0.f, 0.f};
#pragma unroll
    for (int i = 0; i < 4; i++)
#pragma unroll
        for (int j = 0; j < 4; j++) acc[i][j] = zero4;

    for (int kt = 0; kt < NT; ++kt) {
        const int buf = kt & 1;
        __syncthreads();   // drains async(kt)
        if (kt + 1 < NT) stage(buf ^ 1, kt + 1);

        bf16x8 af[4], bfr[4];
#pragma unroll
        for (int i = 0; i < 4; i++) {
            const int m = wm + i * 16 + l16;
            af[i]  = *(const bf16x8*)&sA[buf][m * GBK + (q4 ^ (m & 3)) * 8];
            const int n = wn + i * 16 + l16;
            bfr[i] = *(const bf16x8*)&sW[buf][n * GBK + (q4 ^ (n & 3)) * 8];
        }
#pragma unroll
        for (int i = 0; i < 4; i++)
#pragma unroll
            for (int j = 0; j < 4; j++)
                acc[i][j] = __builtin_amdgcn_mfma_f32_16x16x32_bf16(af[i], bfr[j], acc[i][j], 0, 0, 0);
    }

#pragma unroll
    for (int j = 0; j < 4; j++) {
        const int col = bn0 + wn + j * 16 + l16;
        const float bj = bias[col];
#pragma unroll
        for (int i = 0; i < 4; i++) {
            const int rowb = bm0 + wm + i * 16 + q4 * 4;
#pragma unroll
            for (int r = 0; r < 4; r++)
                C[(size_t)(rowb + r) * D_MODEL + col] = acc[i][j][r] + bj;
        }
    }
}

// ---------------------------------------------------------------------------
// Flash attention. grid = (B*H=64, S/256=8), 512 thr = 8 waves; wave owns 32
// q-rows. Double-buffered K / permuted V^T, one raw s_barrier + vmcnt(0) per
// tile, stage(t+1) under compute(t). Swapped QK^T (qb pre-scaled 0.125, kb
// pre-scaled log2e): lane holds S[qrow=l16][key=16*ng+q4*4+r]; softmax is
// bare exp2; P packed via v_cvt_pk_bf16_f32 directly into PV A-fragments
// (V^T written with matching per-32-key permutation). Row sums via ones-MFMA
// (layout row=q4*4+r lands sums on the storing lanes -> no shuffle reduce).
// ---------------------------------------------------------------------------
#define KVT (S_LEN / 128)   // 16 key tiles

__global__ __launch_bounds__(512, 3) void attn_fused(
    const bf16_t* __restrict__ q, const bf16_t* __restrict__ k,
    const bf16_t* __restrict__ vt, bf16_t* o)
{
    __align__(16) __shared__ bf16_t sK[2][128 * 64];   // [key][dh], 8-chunk swizzle
    __align__(16) __shared__ bf16_t sVt[2][64 * 128];  // [dh][key-perm], 16-chunk swizzle

    const int t    = threadIdx.x;
    const int lane = t & 63;
    const int w    = t >> 6;                 // 0..7
    const int head = blockIdx.x;             // 0..63
    const int b    = head >> 4;
    const int h    = head & 15;
    const size_t base = (size_t)b * S_LEN * D_MODEL + (size_t)h * HEAD_DIM;
    const bf16_t* vth = vt + ((size_t)b * 1024 + h * 64) * 2048;  // [dh][s-perm]
    const int qt0  = blockIdx.y * 256;
    const int q4   = lane >> 4;
    const int l16  = lane & 15;

    // q fragments: straight copy (0.125 folded into the Q projection)
    bf16x8 qf[2][2];
#pragma unroll
    for (int mg = 0; mg < 2; mg++)
#pragma unroll
        for (int kk = 0; kk < 2; kk++)
            qf[mg][kk] = *(const bf16x8*)&q[base + (size_t)(qt0 + w * 32 + mg * 16 + l16) * D_MODEL + kk * 32 + q4 * 8];

    const f32x4 zero4 = {0.f, 0.f, 0.f, 0.f};
    f32x4 oacc[2][4];
#pragma unroll
    for (int mg = 0; mg < 2; mg++)
#pragma unroll
        for (int g = 0; g < 4; g++) oacc[mg][g] = zero4;
    f32x4 sacc[2] = {zero4, zero4};          // row sums via ones-MFMA

    bf16x8 ones;
#pragma unroll
    for (int j = 0; j < 8; j++) ones[j] = (bf16_t)1.0f;

    auto stage = [&](int bf, int kt) {
        const int key0 = kt * 128;
#pragma unroll
        for (int i = 0; i < 2; i++) {
            const int cid = i * 512 + t;           // 1024 16B chunks of K
            const int row = cid >> 3;
            const int cg  = (cid & 7) ^ (row & 7);
            async_copy16(&sK[bf][cid * 8], &k[base + (size_t)(key0 + row) * D_MODEL + cg * 8]);
        }
#pragma unroll
        for (int i = 0; i < 2; i++) {
            const int cid = i * 512 + t;           // 1024 16B chunks of V^T
            const int dh  = cid >> 4;
            const int cg  = (cid & 15) ^ (dh & 15);
            async_copy16(&sVt[bf][cid * 8], &vth[(size_t)dh * 2048 + key0 + cg * 8]);
        }
    };

    stage(0, 0);
    asm volatile("s_waitcnt vmcnt(0)" ::: "memory");
    __builtin_amdgcn_s_barrier();
    __builtin_amdgcn_sched_barrier(0);

    for (int kt = 0; kt < KVT; ++kt) {
        const int cur = kt & 1;
        if (kt < KVT - 1) stage(cur ^ 1, kt + 1);   // flies under compute

#pragma unroll
        for (int hh = 0; hh < 2; hh++) {
            // S^T = K @ Q^T : first k-slice reads zero4 as C (no acc copies)
            f32x4 sc[2][4];
            __builtin_amdgcn_s_setprio(1);
#pragma unroll
            for (int ngl = 0; ngl < 4; ngl++) {
                const int key = (hh * 4 + ngl) * 16 + l16;
                const bf16x8 kf0 = *(const bf16x8*)&sK[cur][key * 64 + ((q4) ^ (key & 7)) * 8];
                const bf16x8 kf1 = *(const bf16x8*)&sK[cur][key * 64 + ((4 + q4) ^ (key & 7)) * 8];
#pragma unroll
                for (int mg = 0; mg < 2; mg++) {
                    sc[mg][ngl] = __builtin_amdgcn_mfma_f32_16x16x32_bf16(kf0, qf[mg][0], zero4, 0, 0, 0);
                    sc[mg][ngl] = __builtin_amdgcn_mfma_f32_16x16x32_bf16(kf1, qf[mg][1], sc[mg][ngl], 0, 0, 0);
                }
            }
            __builtin_amdgcn_s_setprio(0);

            // softmax: p = 2^s (kb carries log2e); pack pairs straight into
            // PV A-fragments via v_cvt_pk_bf16_f32.
            // pf element j of chunk cl holds key c*32 + (j>>2)*16 + q4*4 + (j&3)
            bf16x8 pf[2][2];
#pragma unroll
            for (int mg = 0; mg < 2; mg++) {
#pragma unroll
                for (int ngl = 0; ngl < 4; ngl++)
#pragma unroll
                    for (int r = 0; r < 4; r++)
                        sc[mg][ngl][r] = exp2f(sc[mg][ngl][r]);
#pragma unroll
                for (int cl = 0; cl < 2; cl++) {
                    union { uint32_t u[4]; bf16x8 v; } pk;
#pragma unroll
                    for (int dw = 0; dw < 4; dw++) {
                        const int c = cl * 2 + (dw >> 1);
                        const int e = (dw & 1) * 2;
                        pk.u[dw] = cvt_pk_bf16(sc[mg][c][e], sc[mg][c][e + 1]);
                    }
                    pf[mg][cl] = pk.v;
                }
            }

            // PV + row-sum MFMAs (V^T stored in matching permuted k-order)
            __builtin_amdgcn_s_setprio(1);
#pragma unroll
            for (int cl = 0; cl < 2; cl++) {
                const int cb = (hh * 2 + cl) * 4;
#pragma unroll
                for (int g = 0; g < 4; g++) {
                    const int dh = g * 16 + l16;
                    const bf16x8 vf = *(const bf16x8*)&sVt[cur][dh * 128 + ((cb + q4) ^ l16) * 8];
#pragma unroll
                    for (int mg = 0; mg < 2; mg++)
                        oacc[mg][g] = __builtin_amdgcn_mfma_f32_16x16x32_bf16(pf[mg][cl], vf, oacc[mg][g], 0, 0, 0);
                }
#pragma unroll
                for (int mg = 0; mg < 2; mg++)
                    sacc[mg] = __builtin_amdgcn_mfma_f32_16x16x32_bf16(pf[mg][cl], ones, sacc[mg], 0, 0, 0);
            }
            __builtin_amdgcn_s_setprio(0);
        }

        asm volatile("s_waitcnt vmcnt(0)" ::: "memory");
        __builtin_amdgcn_s_barrier();
        __builtin_amdgcn_sched_barrier(0);
    }

    // normalize + store: sacc[mg][r] holds the full row sum for qrow q4*4+r
    // (every col slot equal) -- exactly this lane's output rows, no shuffle.
#pragma unroll
    for (int mg = 0; mg < 2; mg++)
#pragma unroll
        for (int r = 0; r < 4; r++) {
            const float inv = 1.0f / sacc[mg][r];
            const size_t rowoff = base + (size_t)(qt0 + w * 32 + mg * 16 + q4 * 4 + r) * D_MODEL;
#pragma unroll
            for (int g = 0; g < 4; g++)
                o[rowoff + g * 16 + l16] = (bf16_t)(oacc[mg][g][r] * inv);
        }
}

// ---------------------------------------------------------------------------
// Buffer plan (ws = 33.55 MB, d_out = 32 MiB fp32 output):
//   ws:    qb [0,16.78MB) | vb [16.78,33.55MB)
//   d_out: kb (bf16) [0,16MiB) | Wq/Wk/Wv bf16 [16,22.3MiB)
//   Wo-bf16 -> vb region (dead after attn). ob aliases qb.
// Order: convW(q,k,v) -> proj -> attn -> convW(o) -> out.
// ---------------------------------------------------------------------------
extern "C" void kernel_launch(void* const* d_in, const int* in_sizes, int n_in,
                              void* d_out, int out_size, void* d_ws, size_t ws_size,
                              hipStream_t stream) {
    const float* Q  = (const float*)d_in[0];
    const float* K  = (const float*)d_in[1];
    const float* V  = (const float*)d_in[2];
    const float* Wq = (const float*)d_in[3];
    const float* bq = (const float*)d_in[4];
    const float* Wk = (const float*)d_in[5];
    const float* bk = (const float*)d_in[6];
    const float* Wv = (const float*)d_in[7];
    const float* bv = (const float*)d_in[8];
    const float* Wo = (const float*)d_in[9];
    const float* bo = (const float*)d_in[10];
    float* out = (float*)d_out;

    bf16_t* qb  = (bf16_t*)d_ws;
    bf16_t* vb  = qb + (size_t)M_ROWS * D_MODEL;
    bf16_t* kb  = (bf16_t*)d_out;
    bf16_t* wqb = kb + (size_t)M_ROWS * D_MODEL;     // d_out + 16 MiB
    bf16_t* wkb = wqb + (size_t)D_MODEL * D_MODEL;
    bf16_t* wvb = wkb + (size_t)D_MODEL * D_MODEL;
    bf16_t* wob = vb;                                 // vb dead after attn
    bf16_t* ob  = qb;

    conv_w<<<dim3(512, 3), dim3(256), 0, stream>>>(Wq, Wk, Wv, wqb, wkb, wvb);
    gemm_proj<<<dim3(8, 64, 3), dim3(256), 0, stream>>>(Q, wqb, bq, K, wkb, bk, V, wvb, bv, qb, kb, vb);
    attn_fused<<<dim3(4 * N_HEADS, S_LEN / 256), dim3(512), 0, stream>>>(qb, kb, vb, ob);
    conv_w<<<dim3(512, 1), dim3(256), 0, stream>>>(Wo, Wo, Wo, wob, wob, wob);
    gemm_out<<<dim3(8, 64), dim3(256), 0, stream>>>(ob, wob, bo, out);
}

// Round 5
// 358.335 us; speedup vs baseline: 1.4315x; 1.0491x over previous
//
#include <hip/hip_runtime.h>
#include <hip/hip_bf16.h>
#include <stdint.h>
#include <stddef.h>

// ---------------------------------------------------------------------------
// MultiHeadAttention: q/k/v = X @ W.T + b ; flash-attn per head ; out @ Wo.T+bo
// FP32 in/out buffers; bf16 MFMA internally.
// B=4 S=2048 D=1024 H=16 Dh=64 -> M = B*S = 8192
// Round 10: gemm_proj pipeline fix. __syncthreads() was draining vmcnt(0)
// every k-step (killing the A/W prefetch). Now: raw s_barrier + counted
// s_waitcnt vmcnt(4) -- the 4 outstanding ops are the kt+2 A-tile fp32 loads,
// which survive the barrier (2 bodies of latency cover); W async gets 1 body.
// A cvt+ds_write moved after the MFMA cluster (targets the other buffer).
// Bank-conflict fix in proj sW + gemm_out sA/sW: swizzle (row&3) ->
// ((row>>1)&3) (row stride is 64B=16 banks, so rows 2 apart alias; the old
// XOR gave 4-way conflicts -> 6.3M SQ_LDS_BANK_CONFLICT).
// attn unchanged from round 9.
// ---------------------------------------------------------------------------

typedef __bf16 bf16_t;
typedef __bf16 bf16x4 __attribute__((ext_vector_type(4)));
typedef __bf16 bf16x8 __attribute__((ext_vector_type(8)));
typedef float f32x4 __attribute__((ext_vector_type(4)));

#define D_MODEL 1024
#define M_ROWS  8192
#define S_LEN   2048
#define N_HEADS 16
#define HEAD_DIM 64
#define GBK 32
#define NT (D_MODEL / GBK)   // 32 k-tiles

__device__ __forceinline__ void async_copy16(void* lds, const void* g) {
    __builtin_amdgcn_global_load_lds(
        (const __attribute__((address_space(1))) void*)g,
        (__attribute__((address_space(3))) void*)lds, 16, 0, 0);
}

__device__ __forceinline__ uint32_t cvt_pk_bf16(float lo, float hi) {
    uint32_t r;
    asm("v_cvt_pk_bf16_f32 %0, %1, %2" : "=v"(r) : "v"(lo), "v"(hi));
    return r;
}

// ---------------------------------------------------------------------------
// fp32 -> bf16 conversion (W matrices, 1M elems each). grid (512, nmat).
// ---------------------------------------------------------------------------
__global__ __launch_bounds__(256) void conv_w(
    const float* __restrict__ s0, const float* __restrict__ s1, const float* __restrict__ s2,
    bf16_t* __restrict__ d0, bf16_t* __restrict__ d1, bf16_t* __restrict__ d2)
{
    const float* s; bf16_t* d;
    if (blockIdx.y == 0)      { s = s0; d = d0; }
    else if (blockIdx.y == 1) { s = s1; d = d1; }
    else                      { s = s2; d = d2; }
    const int i = (blockIdx.x * 256 + threadIdx.x) * 8;
    const f32x4 a = *(const f32x4*)(s + i);
    const f32x4 b = *(const f32x4*)(s + i + 4);
    bf16x8 o;
#pragma unroll
    for (int j = 0; j < 4; j++) { o[j] = (bf16_t)a[j]; o[4 + j] = (bf16_t)b[j]; }
    *(bf16x8*)(d + i) = o;
}

// ---------------------------------------------------------------------------
// Projection GEMM: C[m,n] = sum_k A[m,k]*W[n,k] + bias[n]
// A fp32 (reg-staged, 2-deep, loads LIVE ACROSS the barrier via vmcnt(4));
// W bf16 (global_load_lds, 1 body ahead); bias fp32; C bf16.
// 128x128 tile, BK=32, 256 thr (4 waves, 2x2 of 64x64). Raw s_barrier +
// counted vmcnt per k-step. XCD-chunked swizzle (A panel L2-resident).
// z==0 (Q): output scaled 0.125. z==1 (K): scaled log2e. z==2 (V): transposed
// per head [b][dh][s] with per-32-key permutation.
// ---------------------------------------------------------------------------
__global__ __launch_bounds__(256, 3) void gemm_proj(
    const float* __restrict__ A0, const bf16_t* __restrict__ W0, const float* __restrict__ b0,
    const float* __restrict__ A1, const bf16_t* __restrict__ W1, const float* __restrict__ b1,
    const float* __restrict__ A2, const bf16_t* __restrict__ W2, const float* __restrict__ b2,
    bf16_t* C0, bf16_t* C1, bf16_t* C2)
{
    const int lin = blockIdx.x + ((int)blockIdx.y << 3) + ((int)blockIdx.z << 9);
    const int nl  = (lin & 7) * 192 + (lin >> 3);          // bijective, 1536%8==0
    const int z   = nl >> 9;
    const int rem = nl & 511;
    const int bm0 = (rem >> 3) * 128;
    const int bn0 = (rem & 7) * 128;

    const float* A; const bf16_t* W; const float* bias; bf16_t* C;
    if (z == 0)      { A = A0; W = W0; bias = b0; C = C0; }
    else if (z == 1) { A = A1; W = W1; bias = b1; C = C1; }
    else             { A = A2; W = W2; bias = b2; C = C2; }
    const float cs = (z == 0) ? 0.125f : (z == 1) ? 1.4426950408889634f : 1.0f;

    __align__(16) __shared__ bf16_t sA[2][128 * 36];   // padded rows (72B stride)
    __align__(16) __shared__ bf16_t sW[2][128 * GBK];  // linear: async dest

    const int t    = threadIdx.x;
    const int lane = t & 63;
    const int w    = t >> 6;
    const int wm   = (w & 1) * 64;
    const int wn   = (w >> 1) * 64;
    const int q4   = lane >> 4;
    const int l16  = lane & 15;

    const int srow  = t >> 1;
    const int cbase = (t & 1) * 2;
    const float* aptr = &A[(size_t)(bm0 + srow) * D_MODEL + cbase * 8];

    // W staging: source chunk cg = cl ^ ((row>>1)&3)  (bank-conflict-free read)
    auto stageW = [&](int buf, int kt) {
#pragma unroll
        for (int i = 0; i < 2; i++) {
            const int cid = i * 256 + t;
            const int row = cid >> 2;
            const int cg  = (cid & 3) ^ ((row >> 1) & 3);
            async_copy16(&sW[buf][cid * 8],
                         &W[(size_t)(bn0 + row) * D_MODEL + kt * GBK + cg * 8]);
        }
    };
    // A LDS write: chunk c at slot c ^ (srow&3)  (72B row stride, read matches)
    auto writeA = [&](int buf, f32x4 (&ar)[4]) {
        bf16x8 abf[2];
#pragma unroll
        for (int c = 0; c < 4; c++)
#pragma unroll
            for (int j = 0; j < 4; j++)
                abf[c >> 1][(c & 1) * 4 + j] = (bf16_t)ar[c][j];
#pragma unroll
        for (int hb = 0; hb < 2; hb++) {
            const int slot = (cbase + hb) ^ (srow & 3);
            *(bf16x8*)&sA[buf][srow * 36 + slot * 8] = abf[hb];
        }
    };

    // preamble: W(0) async; A(0)->arA, A(1)->arB; sA[0] <- arA; publish.
    stageW(0, 0);
    f32x4 arA[4], arB[4];
#pragma unroll
    for (int c = 0; c < 4; c++) arA[c] = *(const f32x4*)(aptr + c * 4);
#pragma unroll
    for (int c = 0; c < 4; c++) arB[c] = *(const f32x4*)(aptr + GBK + c * 4);
    writeA(0, arA);    // compiler waits arA (vmcnt(4): arB stays in flight)
    asm volatile("s_waitcnt vmcnt(4) lgkmcnt(0)" ::: "memory");  // W(0) home too
    __builtin_amdgcn_s_barrier();
    __builtin_amdgcn_sched_barrier(0);

    f32x4 acc[4][4];
    const f32x4 zero4 = {0.f, 0.f, 0.f, 0.f};
#pragma unroll
    for (int i = 0; i < 4; i++)
#pragma unroll
        for (int j = 0; j < 4; j++) acc[i][j] = zero4;

    // body(kt): compute buf; stage W(kt+1)+A(kt+1)->LDS buf^1; load A(kt+2).
    // arCur holds A(kt+1); arNext receives A(kt+2).
    auto body = [&](int kt, int buf, f32x4 (&arCur)[4], f32x4 (&arNext)[4]) {
        if (kt + 1 < NT) stageW(buf ^ 1, kt + 1);            // 2 vm (oldest)
        if (kt + 2 < NT) {
            const float* ap = aptr + (size_t)(kt + 2) * GBK;
#pragma unroll
            for (int c = 0; c < 4; c++) arNext[c] = *(const f32x4*)(ap + c * 4);
        }

        bf16x8 af[4], bfr[4];
#pragma unroll
        for (int i = 0; i < 4; i++) {
            const int m = wm + i * 16 + l16;
            af[i]  = *(const bf16x8*)&sA[buf][m * 36 + (q4 ^ (m & 3)) * 8];
            const int n = wn + i * 16 + l16;
            bfr[i] = *(const bf16x8*)&sW[buf][n * GBK + (q4 ^ ((n >> 1) & 3)) * 8];
        }
#pragma unroll
        for (int i = 0; i < 4; i++)
#pragma unroll
            for (int j = 0; j < 4; j++)
                acc[i][j] = __builtin_amdgcn_mfma_f32_16x16x32_bf16(af[i], bfr[j], acc[i][j], 0, 0, 0);

        // A(kt+1) -> sA[buf^1] AFTER the MFMAs (arCur's vmcnt lands late)
        __builtin_amdgcn_sched_barrier(0);
        if (kt + 1 < NT) writeA(buf ^ 1, arCur);
        // W(kt+1) + sA writes must be home; arNext (4 loads) stays in flight.
        if (kt + 2 < NT) asm volatile("s_waitcnt vmcnt(4) lgkmcnt(0)" ::: "memory");
        else             asm volatile("s_waitcnt vmcnt(0) lgkmcnt(0)" ::: "memory");
        __builtin_amdgcn_s_barrier();
        __builtin_amdgcn_sched_barrier(0);
    };

    for (int kt = 0; kt < NT; kt += 2) {
        body(kt,     0, arB, arA);
        body(kt + 1, 1, arA, arB);
    }

    if (z != 2) {
#pragma unroll
        for (int j = 0; j < 4; j++) {
            const int col = bn0 + wn + j * 16 + l16;
            const float bj = bias[col];
#pragma unroll
            for (int i = 0; i < 4; i++) {
                const int rowb = bm0 + wm + i * 16 + q4 * 4;
#pragma unroll
                for (int r = 0; r < 4; r++)
                    C[(size_t)(rowb + r) * D_MODEL + col] = (bf16_t)((acc[i][j][r] + bj) * cs);
            }
        }
    } else {
        const int bb = bm0 >> 11;          // batch (tile never straddles)
        const int sbase = (bm0 & 2047) + wm;
#pragma unroll
        for (int j = 0; j < 4; j++) {
            const int col = bn0 + wn + j * 16 + l16;
            const float bj = bias[col];
            bf16_t* ct = C + ((size_t)bb * 1024 + col) * 2048;
#pragma unroll
            for (int i = 0; i < 4; i++) {
                const int s0 = sbase + i * 16 + q4 * 4;
                // permute: c*32 + g*16 + p*4  ->  c*32 + p*8 + g*4
                const int s0p = (s0 & ~31) | (((s0 >> 2) & 3) << 3) | (((s0 >> 4) & 1) << 2);
                bf16x4 v4;
#pragma unroll
                for (int r = 0; r < 4; r++) v4[r] = (bf16_t)(acc[i][j][r] + bj);
                *(bf16x4*)&ct[s0p] = v4;
            }
        }
    }
}

// ---------------------------------------------------------------------------
// Output GEMM: A bf16 (attention out), W bf16 (pre-converted Wo), bias fp32,
// C fp32 (d_out). BOTH operands via global_load_lds, double-buffered, one
// barrier per iteration, XCD-chunked swizzle. ((row>>1)&3) swizzle:
// conflict-free fragment reads.
// ---------------------------------------------------------------------------
__global__ __launch_bounds__(256, 3) void gemm_out(
    const bf16_t* __restrict__ A, const bf16_t* __restrict__ W,
    const float* __restrict__ bias, float* __restrict__ C)
{
    const int lin = blockIdx.x + ((int)blockIdx.y << 3);
    const int nl  = (lin & 7) * 64 + (lin >> 3);           // bijective, 512%8==0
    const int bm0 = (nl >> 3) * 128;
    const int bn0 = (nl & 7) * 128;

    __align__(16) __shared__ bf16_t sA[2][128 * GBK];
    __align__(16) __shared__ bf16_t sW[2][128 * GBK];

    const int t    = threadIdx.x;
    const int lane = t & 63;
    const int w    = t >> 6;
    const int wm   = (w & 1) * 64;
    const int wn   = (w >> 1) * 64;
    const int q4   = lane >> 4;
    const int l16  = lane & 15;

    auto stage = [&](int buf, int kt) {
#pragma unroll
        for (int i = 0; i < 2; i++) {
            const int cid = i * 256 + t;
            const int row = cid >> 2;
            const int cg  = (cid & 3) ^ ((row >> 1) & 3);
            async_copy16(&sA[buf][cid * 8],
                         &A[(size_t)(bm0 + row) * D_MODEL + kt * GBK + cg * 8]);
            async_copy16(&sW[buf][cid * 8],
                         &W[(size_t)(bn0 + row) * D_MODEL + kt * GBK + cg * 8]);
        }
    };

    stage(0, 0);

    f32x4 acc[4][4];
    const f32x4 zero4 = {0.f, 0.f, 0.f, 0.f};
#pragma unroll
    for (int i = 0; i < 4; i++)
#pragma unroll
        for (int j = 0; j < 4; j++) acc[i][j] = zero4;

    for (int kt = 0; kt < NT; ++kt) {
        const int buf = kt & 1;
        __syncthreads();   // drains async(kt)
        if (kt + 1 < NT) stage(buf ^ 1, kt + 1);

        bf16x8 af[4], bfr[4];
#pragma unroll
        for (int i = 0; i < 4; i++) {
            const int m = wm + i * 16 + l16;
            af[i]  = *(const bf16x8*)&sA[buf][m * GBK + (q4 ^ ((m >> 1) & 3)) * 8];
            const int n = wn + i * 16 + l16;
            bfr[i] = *(const bf16x8*)&sW[buf][n * GBK + (q4 ^ ((n >> 1) & 3)) * 8];
        }
#pragma unroll
        for (int i = 0; i < 4; i++)
#pragma unroll
            for (int j = 0; j < 4; j++)
                acc[i][j] = __builtin_amdgcn_mfma_f32_16x16x32_bf16(af[i], bfr[j], acc[i][j], 0, 0, 0);
    }

#pragma unroll
    for (int j = 0; j < 4; j++) {
        const int col = bn0 + wn + j * 16 + l16;
        const float bj = bias[col];
#pragma unroll
        for (int i = 0; i < 4; i++) {
            const int rowb = bm0 + wm + i * 16 + q4 * 4;
#pragma unroll
            for (int r = 0; r < 4; r++)
                C[(size_t)(rowb + r) * D_MODEL + col] = acc[i][j][r] + bj;
        }
    }
}

// ---------------------------------------------------------------------------
// Flash attention (unchanged from round 9). grid = (B*H=64, S/256=8), 512 thr
// = 8 waves. Double-buffered K / permuted V^T, one raw s_barrier + vmcnt(0)
// per tile. Swapped QK^T (qb pre-scaled 0.125, kb pre-scaled log2e); P via
// v_cvt_pk_bf16_f32 straight into PV A-fragments; row sums via ones-MFMA.
// ---------------------------------------------------------------------------
#define KVT (S_LEN / 128)   // 16 key tiles

__global__ __launch_bounds__(512, 3) void attn_fused(
    const bf16_t* __restrict__ q, const bf16_t* __restrict__ k,
    const bf16_t* __restrict__ vt, bf16_t* o)
{
    __align__(16) __shared__ bf16_t sK[2][128 * 64];   // [key][dh], 8-chunk swizzle
    __align__(16) __shared__ bf16_t sVt[2][64 * 128];  // [dh][key-perm], 16-chunk swizzle

    const int t    = threadIdx.x;
    const int lane = t & 63;
    const int w    = t >> 6;                 // 0..7
    const int head = blockIdx.x;             // 0..63
    const int b    = head >> 4;
    const int h    = head & 15;
    const size_t base = (size_t)b * S_LEN * D_MODEL + (size_t)h * HEAD_DIM;
    const bf16_t* vth = vt + ((size_t)b * 1024 + h * 64) * 2048;  // [dh][s-perm]
    const int qt0  = blockIdx.y * 256;
    const int q4   = lane >> 4;
    const int l16  = lane & 15;

    bf16x8 qf[2][2];
#pragma unroll
    for (int mg = 0; mg < 2; mg++)
#pragma unroll
        for (int kk = 0; kk < 2; kk++)
            qf[mg][kk] = *(const bf16x8*)&q[base + (size_t)(qt0 + w * 32 + mg * 16 + l16) * D_MODEL + kk * 32 + q4 * 8];

    const f32x4 zero4 = {0.f, 0.f, 0.f, 0.f};
    f32x4 oacc[2][4];
#pragma unroll
    for (int mg = 0; mg < 2; mg++)
#pragma unroll
        for (int g = 0; g < 4; g++) oacc[mg][g] = zero4;
    f32x4 sacc[2] = {zero4, zero4};          // row sums via ones-MFMA

    bf16x8 ones;
#pragma unroll
    for (int j = 0; j < 8; j++) ones[j] = (bf16_t)1.0f;

    auto stage = [&](int bf, int kt) {
        const int key0 = kt * 128;
#pragma unroll
        for (int i = 0; i < 2; i++) {
            const int cid = i * 512 + t;           // 1024 16B chunks of K
            const int row = cid >> 3;
            const int cg  = (cid & 7) ^ (row & 7);
            async_copy16(&sK[bf][cid * 8], &k[base + (size_t)(key0 + row) * D_MODEL + cg * 8]);
        }
#pragma unroll
        for (int i = 0; i < 2; i++) {
            const int cid = i * 512 + t;           // 1024 16B chunks of V^T
            const int dh  = cid >> 4;
            const int cg  = (cid & 15) ^ (dh & 15);
            async_copy16(&sVt[bf][cid * 8], &vth[(size_t)dh * 2048 + key0 + cg * 8]);
        }
    };

    stage(0, 0);
    asm volatile("s_waitcnt vmcnt(0)" ::: "memory");
    __builtin_amdgcn_s_barrier();
    __builtin_amdgcn_sched_barrier(0);

    for (int kt = 0; kt < KVT; ++kt) {
        const int cur = kt & 1;
        if (kt < KVT - 1) stage(cur ^ 1, kt + 1);   // flies under compute

#pragma unroll
        for (int hh = 0; hh < 2; hh++) {
            // S^T = K @ Q^T : first k-slice reads zero4 as C (no acc copies)
            f32x4 sc[2][4];
            __builtin_amdgcn_s_setprio(1);
#pragma unroll
            for (int ngl = 0; ngl < 4; ngl++) {
                const int key = (hh * 4 + ngl) * 16 + l16;
                const bf16x8 kf0 = *(const bf16x8*)&sK[cur][key * 64 + ((q4) ^ (key & 7)) * 8];
                const bf16x8 kf1 = *(const bf16x8*)&sK[cur][key * 64 + ((4 + q4) ^ (key & 7)) * 8];
#pragma unroll
                for (int mg = 0; mg < 2; mg++) {
                    sc[mg][ngl] = __builtin_amdgcn_mfma_f32_16x16x32_bf16(kf0, qf[mg][0], zero4, 0, 0, 0);
                    sc[mg][ngl] = __builtin_amdgcn_mfma_f32_16x16x32_bf16(kf1, qf[mg][1], sc[mg][ngl], 0, 0, 0);
                }
            }
            __builtin_amdgcn_s_setprio(0);

            // softmax: p = 2^s (kb carries log2e); pack pairs straight into
            // PV A-fragments via v_cvt_pk_bf16_f32.
            bf16x8 pf[2][2];
#pragma unroll
            for (int mg = 0; mg < 2; mg++) {
#pragma unroll
                for (int ngl = 0; ngl < 4; ngl++)
#pragma unroll
                    for (int r = 0; r < 4; r++)
                        sc[mg][ngl][r] = exp2f(sc[mg][ngl][r]);
#pragma unroll
                for (int cl = 0; cl < 2; cl++) {
                    union { uint32_t u[4]; bf16x8 v; } pk;
#pragma unroll
                    for (int dw = 0; dw < 4; dw++) {
                        const int c = cl * 2 + (dw >> 1);
                        const int e = (dw & 1) * 2;
                        pk.u[dw] = cvt_pk_bf16(sc[mg][c][e], sc[mg][c][e + 1]);
                    }
                    pf[mg][cl] = pk.v;
                }
            }

            // PV + row-sum MFMAs (V^T stored in matching permuted k-order)
            __builtin_amdgcn_s_setprio(1);
#pragma unroll
            for (int cl = 0; cl < 2; cl++) {
                const int cb = (hh * 2 + cl) * 4;
#pragma unroll
                for (int g = 0; g < 4; g++) {
                    const int dh = g * 16 + l16;
                    const bf16x8 vf = *(const bf16x8*)&sVt[cur][dh * 128 + ((cb + q4) ^ l16) * 8];
#pragma unroll
                    for (int mg = 0; mg < 2; mg++)
                        oacc[mg][g] = __builtin_amdgcn_mfma_f32_16x16x32_bf16(pf[mg][cl], vf, oacc[mg][g], 0, 0, 0);
                }
#pragma unroll
                for (int mg = 0; mg < 2; mg++)
                    sacc[mg] = __builtin_amdgcn_mfma_f32_16x16x32_bf16(pf[mg][cl], ones, sacc[mg], 0, 0, 0);
            }
            __builtin_amdgcn_s_setprio(0);
        }

        asm volatile("s_waitcnt vmcnt(0)" ::: "memory");
        __builtin_amdgcn_s_barrier();
        __builtin_amdgcn_sched_barrier(0);
    }

    // normalize + store: sacc[mg][r] holds the full row sum for qrow q4*4+r
#pragma unroll
    for (int mg = 0; mg < 2; mg++)
#pragma unroll
        for (int r = 0; r < 4; r++) {
            const float inv = 1.0f / sacc[mg][r];
            const size_t rowoff = base + (size_t)(qt0 + w * 32 + mg * 16 + q4 * 4 + r) * D_MODEL;
#pragma unroll
            for (int g = 0; g < 4; g++)
                o[rowoff + g * 16 + l16] = (bf16_t)(oacc[mg][g][r] * inv);
        }
}

// ---------------------------------------------------------------------------
// Buffer plan (ws = 33.55 MB, d_out = 32 MiB fp32 output):
//   ws:    qb [0,16.78MB) | vb [16.78,33.55MB)
//   d_out: kb (bf16) [0,16MiB) | Wq/Wk/Wv bf16 [16,22.3MiB)
//   Wo-bf16 -> vb region (dead after attn). ob aliases qb.
// Order: convW(q,k,v) -> proj -> attn -> convW(o) -> out.
// ---------------------------------------------------------------------------
extern "C" void kernel_launch(void* const* d_in, const int* in_sizes, int n_in,
                              void* d_out, int out_size, void* d_ws, size_t ws_size,
                              hipStream_t stream) {
    const float* Q  = (const float*)d_in[0];
    const float* K  = (const float*)d_in[1];
    const float* V  = (const float*)d_in[2];
    const float* Wq = (const float*)d_in[3];
    const float* bq = (const float*)d_in[4];
    const float* Wk = (const float*)d_in[5];
    const float* bk = (const float*)d_in[6];
    const float* Wv = (const float*)d_in[7];
    const float* bv = (const float*)d_in[8];
    const float* Wo = (const float*)d_in[9];
    const float* bo = (const float*)d_in[10];
    float* out = (float*)d_out;

    bf16_t* qb  = (bf16_t*)d_ws;
    bf16_t* vb  = qb + (size_t)M_ROWS * D_MODEL;
    bf16_t* kb  = (bf16_t*)d_out;
    bf16_t* wqb = kb + (size_t)M_ROWS * D_MODEL;     // d_out + 16 MiB
    bf16_t* wkb = wqb + (size_t)D_MODEL * D_MODEL;
    bf16_t* wvb = wkb + (size_t)D_MODEL * D_MODEL;
    bf16_t* wob = vb;                                 // vb dead after attn
    bf16_t* ob  = qb;

    conv_w<<<dim3(512, 3), dim3(256), 0, stream>>>(Wq, Wk, Wv, wqb, wkb, wvb);
    gemm_proj<<<dim3(8, 64, 3), dim3(256), 0, stream>>>(Q, wqb, bq, K, wkb, bk, V, wvb, bv, qb, kb, vb);
    attn_fused<<<dim3(4 * N_HEADS, S_LEN / 256), dim3(512), 0, stream>>>(qb, kb, vb, ob);
    conv_w<<<dim3(512, 1), dim3(256), 0, stream>>>(Wo, Wo, Wo, wob, wob, wob);
    gemm_out<<<dim3(8, 64), dim3(256), 0, stream>>>(ob, wob, bo, out);
}